// Round 2
// baseline (785.988 us; speedup 1.0000x reference)
//
#include <hip/hip_runtime.h>
#include <hip/hip_bf16.h>

#define N_NODES 50000
#define N_EDGES 500000
#define N_GRAPHS 64
#define FDIM 256   // H*HID
#define NHEAD 8
#define NC 10
#define SLOPE 0.2f

// ---------------- CSR build ----------------
__global__ void hist_kernel(const int* __restrict__ dst, int* __restrict__ deg, int E) {
  int e = blockIdx.x * blockDim.x + threadIdx.x;
  if (e < E) atomicAdd(&deg[dst[e]], 1);
}

// single-block exclusive scan of deg[0..n) -> rowstart[0..n]
__global__ void scan_kernel(const int* __restrict__ deg, int* __restrict__ rowstart, int n) {
  __shared__ int wsum[16];
  __shared__ int carry_s;
  int t = threadIdx.x, lane = t & 63, w = t >> 6;
  if (t == 0) carry_s = 0;
  __syncthreads();
  for (int base = 0; base < n; base += 1024) {
    int i = base + t;
    int v = (i < n) ? deg[i] : 0;
    int x = v;
    #pragma unroll
    for (int off = 1; off < 64; off <<= 1) {
      int y = __shfl_up(x, off);
      if (lane >= off) x += y;
    }
    if (lane == 63) wsum[w] = x;
    __syncthreads();
    if (w == 0 && lane < 16) {
      int s = wsum[lane];
      #pragma unroll
      for (int off = 1; off < 16; off <<= 1) {
        int y = __shfl_up(s, off);
        if (lane >= off) s += y;
      }
      wsum[lane] = s;  // inclusive over wave sums
    }
    __syncthreads();
    int woff = (w > 0) ? wsum[w - 1] : 0;
    int incl = x + woff;
    int carry = carry_s;
    if (i < n) rowstart[i] = carry + incl - v;
    __syncthreads();
    if (t == 1023) carry_s = carry + incl;
    __syncthreads();
  }
  if (t == 0) rowstart[n] = carry_s;
}

__global__ void scatter_kernel(const int* __restrict__ src, const int* __restrict__ dst,
                               const int* __restrict__ rowstart, int* __restrict__ cursor,
                               int* __restrict__ esrc, int E) {
  int e = blockIdx.x * blockDim.x + threadIdx.x;
  if (e >= E) return;
  int d = dst[e];
  int p = atomicAdd(&cursor[d], 1);
  esrc[rowstart[d] + p] = src[e];
}

// per-graph node ranges (node2graph is sorted)
__global__ void graph_bounds_kernel(const int* __restrict__ n2g, int* __restrict__ gstart,
                                    int n, int ngraph) {
  int i = blockIdx.x * blockDim.x + threadIdx.x;
  if (i >= n) return;
  int g1 = n2g[i];
  int g0 = (i == 0) ? -1 : n2g[i - 1];
  for (int g = g0 + 1; g <= g1; ++g) gstart[g] = i;
  if (i == n - 1) {
    for (int g = g1 + 1; g <= ngraph; ++g) gstart[g] = n;
  }
}

// ---------------- GEMM: C[N,256] = A[N,K](f32) @ W[K,256](f32), fp32 out ----------------
// block tile 64 rows x 256 cols, thread tile 16 rows x 4 cols, 256 threads
template<int K>
__global__ void gemm_kernel(const float* __restrict__ A, const float* __restrict__ W,
                            float* __restrict__ C, int nrows) {
  __shared__ __align__(16) float Wlds[32][256];
  __shared__ __align__(16) float Alds[32][68];  // [k][row], padded
  int t = threadIdx.x;
  int row0 = blockIdx.x * 64;
  int tx = t & 63;   // cols 4*tx .. 4*tx+3
  int ty = t >> 6;   // rows 16*ty .. 16*ty+15
  float acc[16][4];
  #pragma unroll
  for (int i = 0; i < 16; ++i) {
    acc[i][0] = acc[i][1] = acc[i][2] = acc[i][3] = 0.f;
  }
  for (int kc = 0; kc < K; kc += 32) {
    // stage W chunk: rows kc..kc+31, all 256 cols (8192 contiguous floats)
    #pragma unroll
    for (int rep = 0; rep < 8; ++rep) {
      int lin = rep * 1024 + t * 4;
      float4 v = *(const float4*)(W + (size_t)kc * 256 + lin);
      *(float4*)&Wlds[lin >> 8][lin & 255] = v;
    }
    // stage A chunk transposed: Alds[k][row]
    int r = t >> 3, c4 = (t & 7) * 4;
    #pragma unroll
    for (int half = 0; half < 2; ++half) {
      int rr = r + half * 32;
      int gr = row0 + rr;
      float4 v = make_float4(0.f, 0.f, 0.f, 0.f);
      if (gr < nrows) v = *(const float4*)(A + (size_t)gr * K + kc + c4);
      Alds[c4 + 0][rr] = v.x;
      Alds[c4 + 1][rr] = v.y;
      Alds[c4 + 2][rr] = v.z;
      Alds[c4 + 3][rr] = v.w;
    }
    __syncthreads();
    #pragma unroll 4
    for (int k = 0; k < 32; ++k) {
      float4 wv = *(const float4*)&Wlds[k][tx * 4];
      const float* ap = &Alds[k][ty * 16];
      #pragma unroll
      for (int rr = 0; rr < 16; ++rr) {
        float a = ap[rr];
        acc[rr][0] = fmaf(a, wv.x, acc[rr][0]);
        acc[rr][1] = fmaf(a, wv.y, acc[rr][1]);
        acc[rr][2] = fmaf(a, wv.z, acc[rr][2]);
        acc[rr][3] = fmaf(a, wv.w, acc[rr][3]);
      }
    }
    __syncthreads();
  }
  #pragma unroll
  for (int rr = 0; rr < 16; ++rr) {
    int gr = row0 + ty * 16 + rr;
    if (gr < nrows) {
      float4 v = make_float4(acc[rr][0], acc[rr][1], acc[rr][2], acc[rr][3]);
      *(float4*)&C[(size_t)gr * 256 + tx * 4] = v;
    }
  }
}

// ---------------- attention logits el/er ----------------
__global__ void elr_kernel(const float* __restrict__ fs, const float* __restrict__ al,
                           const float* __restrict__ ar, float* __restrict__ el,
                           float* __restrict__ er, int nnodes) {
  int tid = blockIdx.x * blockDim.x + threadIdx.x;
  if (tid >= nnodes * NHEAD) return;
  int n = tid >> 3, h = tid & 7;
  const float4* f = (const float4*)&fs[(size_t)n * FDIM + h * 32];
  const float4* a4 = (const float4*)(al + h * 32);
  const float4* r4 = (const float4*)(ar + h * 32);
  float sl = 0.f, sr = 0.f;
  #pragma unroll
  for (int i = 0; i < 8; ++i) {
    float4 v = f[i];
    float4 a = a4[i];
    float4 r = r4[i];
    sl += v.x * a.x + v.y * a.y + v.z * a.z + v.w * a.w;
    sr += v.x * r.x + v.y * r.y + v.z * r.z + v.w * r.w;
  }
  el[tid] = sl;
  er[tid] = sr;
}

// ---------------- edge softmax + message aggregation: one wave per dst node ----------------
// lane l handles output elements 4l..4l+3  (head h = l>>3)
template<bool RELU>
__global__ void edge_agg_kernel(const int* __restrict__ rowstart, const int* __restrict__ esrc,
                                const float* __restrict__ el, const float* __restrict__ er,
                                const float* __restrict__ fs, const float* __restrict__ bias,
                                float* __restrict__ out, int nnodes) {
  int gid = blockIdx.x * blockDim.x + threadIdx.x;
  int v = gid >> 6;
  int lane = threadIdx.x & 63;
  if (v >= nnodes) return;
  int h = lane >> 3;
  int row0 = rowstart[v];
  int deg = rowstart[v + 1] - row0;
  float er_vh = er[v * NHEAD + h];
  // phase 1: softmax denominator per head (8 lanes per head split the edges)
  // (no max-subtraction: logits are O(1); exp(x)/sum exp(x) is exact in fp32 here)
  float psum = 0.f;
  for (int j = lane & 7; j < deg; j += 8) {
    int s = esrc[row0 + j];
    float x = el[s * NHEAD + h] + er_vh;
    x = (x >= 0.f) ? x : SLOPE * x;
    psum += __expf(x);
  }
  psum += __shfl_xor(psum, 1);
  psum += __shfl_xor(psum, 2);
  psum += __shfl_xor(psum, 4);
  float rdenom = (deg > 0) ? (1.0f / psum) : 0.f;
  // phase 2: weighted gather of fs[src]
  float4 acc = make_float4(0.f, 0.f, 0.f, 0.f);
  for (int j = 0; j < deg; ++j) {
    int s = esrc[row0 + j];
    float x = el[s * NHEAD + h] + er_vh;
    x = (x >= 0.f) ? x : SLOPE * x;
    float wgt = __expf(x) * rdenom;
    float4 f = *(const float4*)&fs[(size_t)s * FDIM + lane * 4];
    acc.x = fmaf(wgt, f.x, acc.x);
    acc.y = fmaf(wgt, f.y, acc.y);
    acc.z = fmaf(wgt, f.z, acc.z);
    acc.w = fmaf(wgt, f.w, acc.w);
  }
  const float4 b = *(const float4*)(bias + lane * 4);
  acc.x += b.x; acc.y += b.y; acc.z += b.z; acc.w += b.w;
  if (RELU) {
    acc.x = fmaxf(acc.x, 0.f); acc.y = fmaxf(acc.y, 0.f);
    acc.z = fmaxf(acc.z, 0.f); acc.w = fmaxf(acc.w, 0.f);
  }
  *(float4*)&out[(size_t)v * FDIM + lane * 4] = acc;
}

// ---------------- per-graph mean pool ----------------
__global__ void pool_kernel(const float* __restrict__ h2, const int* __restrict__ gstart,
                            float* __restrict__ hg) {
  int g = blockIdx.x;
  int c = blockIdx.y * 64 + threadIdx.x;
  int s = gstart[g], e = gstart[g + 1];
  float sum = 0.f;
  for (int n = s; n < e; ++n) sum += h2[(size_t)n * FDIM + c];
  float cnt = (e > s) ? (float)(e - s) : 1.f;
  hg[g * FDIM + c] = sum / cnt;
}

// ---------------- classifier ----------------
__global__ void classifier_kernel(const float* __restrict__ hg, const float* __restrict__ Wc,
                                  const float* __restrict__ bcv, float* __restrict__ out) {
  int tid = blockIdx.x * blockDim.x + threadIdx.x;
  if (tid >= N_GRAPHS * NC) return;
  int b = tid / NC, j = tid % NC;
  float s = bcv[j];
  for (int c = 0; c < FDIM; ++c) s += hg[b * FDIM + c] * Wc[c * NC + j];
  out[tid] = s;
}

extern "C" void kernel_launch(void* const* d_in, const int* in_sizes, int n_in,
                              void* d_out, int out_size, void* d_ws, size_t ws_size,
                              hipStream_t stream) {
  const float* feat = (const float*)d_in[0];
  const int* src    = (const int*)d_in[1];
  const int* dst    = (const int*)d_in[2];
  const int* n2g    = (const int*)d_in[3];
  const float* W1  = (const float*)d_in[4];
  const float* al1 = (const float*)d_in[5];
  const float* ar1 = (const float*)d_in[6];
  const float* b1  = (const float*)d_in[7];
  const float* W2  = (const float*)d_in[8];
  const float* al2 = (const float*)d_in[9];
  const float* ar2 = (const float*)d_in[10];
  const float* b2  = (const float*)d_in[11];
  const float* Wc  = (const float*)d_in[12];
  const float* bc  = (const float*)d_in[13];
  float* out = (float*)d_out;

  char* wp = (char*)d_ws;
  auto carve = [&](size_t bytes) -> void* {
    void* p = (void*)wp;
    wp += (bytes + 255) & ~(size_t)255;
    return p;
  };
  float* fs      = (float*)carve((size_t)N_NODES * FDIM * 4);      // 51.2 MB
  float* h1      = (float*)carve((size_t)N_NODES * FDIM * 4);      // 51.2 MB (reused as h2)
  float* h2      = h1;   // h1 dead after gemm<256> consumes it; edge_agg layer-2 writes here
  float* el      = (float*)carve((size_t)N_NODES * NHEAD * 4);
  float* er      = (float*)carve((size_t)N_NODES * NHEAD * 4);
  int* rowstart  = (int*)  carve((size_t)(N_NODES + 1) * 4);
  int* cursor    = (int*)  carve((size_t)N_NODES * 4);
  int* esrc      = (int*)  carve((size_t)N_EDGES * 4);
  int* gstart    = (int*)  carve((size_t)(N_GRAPHS + 1) * 4);
  float* hg      = (float*)carve((size_t)N_GRAPHS * FDIM * 4);
  (void)ws_size; (void)n_in; (void)in_sizes; (void)out_size;

  // CSR build (per call; deterministic heavy phase, ~1M cheap int atomics)
  hipMemsetAsync(cursor, 0, (size_t)N_NODES * 4, stream);
  hist_kernel<<<(N_EDGES + 255) / 256, 256, 0, stream>>>(dst, cursor, N_EDGES);
  scan_kernel<<<1, 1024, 0, stream>>>(cursor, rowstart, N_NODES);
  hipMemsetAsync(cursor, 0, (size_t)N_NODES * 4, stream);
  scatter_kernel<<<(N_EDGES + 255) / 256, 256, 0, stream>>>(src, dst, rowstart, cursor, esrc, N_EDGES);
  graph_bounds_kernel<<<(N_NODES + 255) / 256, 256, 0, stream>>>(n2g, gstart, N_NODES, N_GRAPHS);

  // layer 1
  gemm_kernel<128><<<(N_NODES + 63) / 64, 256, 0, stream>>>(feat, W1, fs, N_NODES);
  elr_kernel<<<(N_NODES * NHEAD + 255) / 256, 256, 0, stream>>>(fs, al1, ar1, el, er, N_NODES);
  edge_agg_kernel<true><<<(N_NODES * 64 + 255) / 256, 256, 0, stream>>>(
      rowstart, esrc, el, er, fs, b1, h1, N_NODES);

  // layer 2
  gemm_kernel<256><<<(N_NODES + 63) / 64, 256, 0, stream>>>(h1, W2, fs, N_NODES);
  elr_kernel<<<(N_NODES * NHEAD + 255) / 256, 256, 0, stream>>>(fs, al2, ar2, el, er, N_NODES);
  edge_agg_kernel<false><<<(N_NODES * 64 + 255) / 256, 256, 0, stream>>>(
      rowstart, esrc, el, er, fs, b2, h2, N_NODES);

  // readout
  pool_kernel<<<dim3(N_GRAPHS, 4), 64, 0, stream>>>(h2, gstart, hg);
  classifier_kernel<<<(N_GRAPHS * NC + 255) / 256, 256, 0, stream>>>(hg, Wc, bc, out);
}

// Round 3
// 621.718 us; speedup vs baseline: 1.2642x; 1.2642x over previous
//
#include <hip/hip_runtime.h>
#include <hip/hip_bf16.h>

#define N_NODES 50000
#define N_EDGES 500000
#define N_GRAPHS 64
#define FDIM 256   // H*HID
#define NHEAD 8
#define NC 10
#define SLOPE 0.2f

// ---------------- CSR build ----------------
__global__ void hist_kernel(const int* __restrict__ dst, int* __restrict__ deg, int E) {
  int e = blockIdx.x * blockDim.x + threadIdx.x;
  if (e < E) atomicAdd(&deg[dst[e]], 1);
}

// single-block exclusive scan of deg[0..n) -> rowstart[0..n]
__global__ void scan_kernel(const int* __restrict__ deg, int* __restrict__ rowstart, int n) {
  __shared__ int wsum[16];
  __shared__ int carry_s;
  int t = threadIdx.x, lane = t & 63, w = t >> 6;
  if (t == 0) carry_s = 0;
  __syncthreads();
  for (int base = 0; base < n; base += 1024) {
    int i = base + t;
    int v = (i < n) ? deg[i] : 0;
    int x = v;
    #pragma unroll
    for (int off = 1; off < 64; off <<= 1) {
      int y = __shfl_up(x, off);
      if (lane >= off) x += y;
    }
    if (lane == 63) wsum[w] = x;
    __syncthreads();
    if (w == 0 && lane < 16) {
      int s = wsum[lane];
      #pragma unroll
      for (int off = 1; off < 16; off <<= 1) {
        int y = __shfl_up(s, off);
        if (lane >= off) s += y;
      }
      wsum[lane] = s;  // inclusive over wave sums
    }
    __syncthreads();
    int woff = (w > 0) ? wsum[w - 1] : 0;
    int incl = x + woff;
    int carry = carry_s;
    if (i < n) rowstart[i] = carry + incl - v;
    __syncthreads();
    if (t == 1023) carry_s = carry + incl;
    __syncthreads();
  }
  if (t == 0) rowstart[n] = carry_s;
}

__global__ void scatter_kernel(const int* __restrict__ src, const int* __restrict__ dst,
                               const int* __restrict__ rowstart, int* __restrict__ cursor,
                               int* __restrict__ esrc, int E) {
  int e = blockIdx.x * blockDim.x + threadIdx.x;
  if (e >= E) return;
  int d = dst[e];
  int p = atomicAdd(&cursor[d], 1);
  esrc[rowstart[d] + p] = src[e];
}

// per-graph node ranges (node2graph is sorted)
__global__ void graph_bounds_kernel(const int* __restrict__ n2g, int* __restrict__ gstart,
                                    int n, int ngraph) {
  int i = blockIdx.x * blockDim.x + threadIdx.x;
  if (i >= n) return;
  int g1 = n2g[i];
  int g0 = (i == 0) ? -1 : n2g[i - 1];
  for (int g = g0 + 1; g <= g1; ++g) gstart[g] = i;
  if (i == n - 1) {
    for (int g = g1 + 1; g <= ngraph; ++g) gstart[g] = n;
  }
}

// ---------------- GEMM: C[N,256] = A[N,K](f32) @ W[K,256](f32), fp32 out ----------------
// block tile 64 rows x 256 cols, thread tile 16 rows x 4 cols, 256 threads
template<int K>
__global__ void gemm_kernel(const float* __restrict__ A, const float* __restrict__ W,
                            float* __restrict__ C, int nrows) {
  __shared__ __align__(16) float Wlds[32][256];
  __shared__ __align__(16) float Alds[32][68];  // [k][row], padded
  int t = threadIdx.x;
  int row0 = blockIdx.x * 64;
  int tx = t & 63;   // cols 4*tx .. 4*tx+3
  int ty = t >> 6;   // rows 16*ty .. 16*ty+15
  float acc[16][4];
  #pragma unroll
  for (int i = 0; i < 16; ++i) {
    acc[i][0] = acc[i][1] = acc[i][2] = acc[i][3] = 0.f;
  }
  for (int kc = 0; kc < K; kc += 32) {
    // stage W chunk: rows kc..kc+31, all 256 cols (8192 contiguous floats)
    #pragma unroll
    for (int rep = 0; rep < 8; ++rep) {
      int lin = rep * 1024 + t * 4;
      float4 v = *(const float4*)(W + (size_t)kc * 256 + lin);
      *(float4*)&Wlds[lin >> 8][lin & 255] = v;
    }
    // stage A chunk transposed: Alds[k][row]
    int r = t >> 3, c4 = (t & 7) * 4;
    #pragma unroll
    for (int half = 0; half < 2; ++half) {
      int rr = r + half * 32;
      int gr = row0 + rr;
      float4 v = make_float4(0.f, 0.f, 0.f, 0.f);
      if (gr < nrows) v = *(const float4*)(A + (size_t)gr * K + kc + c4);
      Alds[c4 + 0][rr] = v.x;
      Alds[c4 + 1][rr] = v.y;
      Alds[c4 + 2][rr] = v.z;
      Alds[c4 + 3][rr] = v.w;
    }
    __syncthreads();
    #pragma unroll 4
    for (int k = 0; k < 32; ++k) {
      float4 wv = *(const float4*)&Wlds[k][tx * 4];
      const float* ap = &Alds[k][ty * 16];
      #pragma unroll
      for (int rr = 0; rr < 16; ++rr) {
        float a = ap[rr];
        acc[rr][0] = fmaf(a, wv.x, acc[rr][0]);
        acc[rr][1] = fmaf(a, wv.y, acc[rr][1]);
        acc[rr][2] = fmaf(a, wv.z, acc[rr][2]);
        acc[rr][3] = fmaf(a, wv.w, acc[rr][3]);
      }
    }
    __syncthreads();
  }
  #pragma unroll
  for (int rr = 0; rr < 16; ++rr) {
    int gr = row0 + ty * 16 + rr;
    if (gr < nrows) {
      float4 v = make_float4(acc[rr][0], acc[rr][1], acc[rr][2], acc[rr][3]);
      *(float4*)&C[(size_t)gr * 256 + tx * 4] = v;
    }
  }
}

// ---------------- attention logits el/er ----------------
__global__ void elr_kernel(const float* __restrict__ fs, const float* __restrict__ al,
                           const float* __restrict__ ar, float* __restrict__ el,
                           float* __restrict__ er, int nnodes) {
  int tid = blockIdx.x * blockDim.x + threadIdx.x;
  if (tid >= nnodes * NHEAD) return;
  int n = tid >> 3, h = tid & 7;
  const float4* f = (const float4*)&fs[(size_t)n * FDIM + h * 32];
  const float4* a4 = (const float4*)(al + h * 32);
  const float4* r4 = (const float4*)(ar + h * 32);
  float sl = 0.f, sr = 0.f;
  #pragma unroll
  for (int i = 0; i < 8; ++i) {
    float4 v = f[i];
    float4 a = a4[i];
    float4 r = r4[i];
    sl += v.x * a.x + v.y * a.y + v.z * a.z + v.w * a.w;
    sr += v.x * r.x + v.y * r.y + v.z * r.z + v.w * r.w;
  }
  el[tid] = sl;
  er[tid] = sr;
}

// ---------------- edge softmax + message aggregation: one wave per dst node ----------------
// lane l handles output elements 4l..4l+3  (head h = l>>3)
template<bool RELU>
__global__ void edge_agg_kernel(const int* __restrict__ rowstart, const int* __restrict__ esrc,
                                const float* __restrict__ el, const float* __restrict__ er,
                                const float* __restrict__ fs, const float* __restrict__ bias,
                                float* __restrict__ out, int nnodes) {
  int gid = blockIdx.x * blockDim.x + threadIdx.x;
  int v = gid >> 6;
  int lane = threadIdx.x & 63;
  if (v >= nnodes) return;
  int h = lane >> 3;
  int row0 = rowstart[v];
  int deg = rowstart[v + 1] - row0;
  float er_vh = er[v * NHEAD + h];
  // phase 1: softmax denominator per head (8 lanes per head split the edges)
  float psum = 0.f;
  for (int j = lane & 7; j < deg; j += 8) {
    int s = esrc[row0 + j];
    float x = el[s * NHEAD + h] + er_vh;
    x = (x >= 0.f) ? x : SLOPE * x;
    psum += __expf(x);
  }
  psum += __shfl_xor(psum, 1);
  psum += __shfl_xor(psum, 2);
  psum += __shfl_xor(psum, 4);
  float rdenom = (deg > 0) ? (1.0f / psum) : 0.f;
  // phase 2: weighted gather of fs[src]
  float4 acc = make_float4(0.f, 0.f, 0.f, 0.f);
  for (int j = 0; j < deg; ++j) {
    int s = esrc[row0 + j];
    float x = el[s * NHEAD + h] + er_vh;
    x = (x >= 0.f) ? x : SLOPE * x;
    float wgt = __expf(x) * rdenom;
    float4 f = *(const float4*)&fs[(size_t)s * FDIM + lane * 4];
    acc.x = fmaf(wgt, f.x, acc.x);
    acc.y = fmaf(wgt, f.y, acc.y);
    acc.z = fmaf(wgt, f.z, acc.z);
    acc.w = fmaf(wgt, f.w, acc.w);
  }
  const float4 b = *(const float4*)(bias + lane * 4);
  acc.x += b.x; acc.y += b.y; acc.z += b.z; acc.w += b.w;
  if (RELU) {
    acc.x = fmaxf(acc.x, 0.f); acc.y = fmaxf(acc.y, 0.f);
    acc.z = fmaxf(acc.z, 0.f); acc.w = fmaxf(acc.w, 0.f);
  }
  *(float4*)&out[(size_t)v * FDIM + lane * 4] = acc;
}

// ---------------- per-graph sum pool (node-parallel, register-accumulated) ----------------
// one wave per 64-node chunk; lane l accumulates channels 4l..4l+3; since n2g is
// sorted, flush atomics only at graph boundaries / chunk end (~220K atomics total)
__global__ void pool_sum_kernel(const float* __restrict__ h2, const int* __restrict__ n2g,
                                float* __restrict__ hg, int nnodes) {
  int wave = (blockIdx.x * blockDim.x + threadIdx.x) >> 6;
  int lane = threadIdx.x & 63;
  int n0 = wave * 64;
  if (n0 >= nnodes) return;
  int n1 = min(n0 + 64, nnodes);
  int curg = n2g[n0];
  float4 acc = make_float4(0.f, 0.f, 0.f, 0.f);
  for (int n = n0; n < n1; ++n) {
    int g = n2g[n];
    if (g != curg) {
      float* p = &hg[(size_t)curg * FDIM + lane * 4];
      atomicAdd(p + 0, acc.x); atomicAdd(p + 1, acc.y);
      atomicAdd(p + 2, acc.z); atomicAdd(p + 3, acc.w);
      acc = make_float4(0.f, 0.f, 0.f, 0.f);
      curg = g;
    }
    float4 v = *(const float4*)&h2[(size_t)n * FDIM + lane * 4];
    acc.x += v.x; acc.y += v.y; acc.z += v.z; acc.w += v.w;
  }
  float* p = &hg[(size_t)curg * FDIM + lane * 4];
  atomicAdd(p + 0, acc.x); atomicAdd(p + 1, acc.y);
  atomicAdd(p + 2, acc.z); atomicAdd(p + 3, acc.w);
}

// ---------------- classifier (divides pooled sums by per-graph count) ----------------
__global__ void classifier_kernel(const float* __restrict__ hgsum, const int* __restrict__ gstart,
                                  const float* __restrict__ Wc, const float* __restrict__ bcv,
                                  float* __restrict__ out) {
  int tid = blockIdx.x * blockDim.x + threadIdx.x;
  if (tid >= N_GRAPHS * NC) return;
  int b = tid / NC, j = tid % NC;
  int cnt = gstart[b + 1] - gstart[b];
  float inv = (cnt > 0) ? (1.0f / (float)cnt) : 1.0f;
  float s = 0.f;
  for (int c = 0; c < FDIM; ++c) s += hgsum[b * FDIM + c] * Wc[c * NC + j];
  out[tid] = s * inv + bcv[j];
}

extern "C" void kernel_launch(void* const* d_in, const int* in_sizes, int n_in,
                              void* d_out, int out_size, void* d_ws, size_t ws_size,
                              hipStream_t stream) {
  const float* feat = (const float*)d_in[0];
  const int* src    = (const int*)d_in[1];
  const int* dst    = (const int*)d_in[2];
  const int* n2g    = (const int*)d_in[3];
  const float* W1  = (const float*)d_in[4];
  const float* al1 = (const float*)d_in[5];
  const float* ar1 = (const float*)d_in[6];
  const float* b1  = (const float*)d_in[7];
  const float* W2  = (const float*)d_in[8];
  const float* al2 = (const float*)d_in[9];
  const float* ar2 = (const float*)d_in[10];
  const float* b2  = (const float*)d_in[11];
  const float* Wc  = (const float*)d_in[12];
  const float* bc  = (const float*)d_in[13];
  float* out = (float*)d_out;

  char* wp = (char*)d_ws;
  auto carve = [&](size_t bytes) -> void* {
    void* p = (void*)wp;
    wp += (bytes + 255) & ~(size_t)255;
    return p;
  };
  float* fs      = (float*)carve((size_t)N_NODES * FDIM * 4);      // 51.2 MB
  float* h1      = (float*)carve((size_t)N_NODES * FDIM * 4);      // 51.2 MB (reused as h2)
  float* h2      = h1;   // h1 dead after gemm<256> consumes it; edge_agg layer-2 writes here
  float* el      = (float*)carve((size_t)N_NODES * NHEAD * 4);
  float* er      = (float*)carve((size_t)N_NODES * NHEAD * 4);
  int* rowstart  = (int*)  carve((size_t)(N_NODES + 1) * 4);
  int* cursor    = (int*)  carve((size_t)N_NODES * 4);
  int* esrc      = (int*)  carve((size_t)N_EDGES * 4);
  int* gstart    = (int*)  carve((size_t)(N_GRAPHS + 1) * 4);
  float* hg      = (float*)carve((size_t)N_GRAPHS * FDIM * 4);
  (void)ws_size; (void)n_in; (void)in_sizes; (void)out_size;

  // CSR build (per call; deterministic heavy phase, ~1M cheap int atomics)
  hipMemsetAsync(cursor, 0, (size_t)N_NODES * 4, stream);
  hipMemsetAsync(hg, 0, (size_t)N_GRAPHS * FDIM * 4, stream);
  hist_kernel<<<(N_EDGES + 255) / 256, 256, 0, stream>>>(dst, cursor, N_EDGES);
  scan_kernel<<<1, 1024, 0, stream>>>(cursor, rowstart, N_NODES);
  hipMemsetAsync(cursor, 0, (size_t)N_NODES * 4, stream);
  scatter_kernel<<<(N_EDGES + 255) / 256, 256, 0, stream>>>(src, dst, rowstart, cursor, esrc, N_EDGES);
  graph_bounds_kernel<<<(N_NODES + 255) / 256, 256, 0, stream>>>(n2g, gstart, N_NODES, N_GRAPHS);

  // layer 1
  gemm_kernel<128><<<(N_NODES + 63) / 64, 256, 0, stream>>>(feat, W1, fs, N_NODES);
  elr_kernel<<<(N_NODES * NHEAD + 255) / 256, 256, 0, stream>>>(fs, al1, ar1, el, er, N_NODES);
  edge_agg_kernel<true><<<(N_NODES * 64 + 255) / 256, 256, 0, stream>>>(
      rowstart, esrc, el, er, fs, b1, h1, N_NODES);

  // layer 2
  gemm_kernel<256><<<(N_NODES + 63) / 64, 256, 0, stream>>>(h1, W2, fs, N_NODES);
  elr_kernel<<<(N_NODES * NHEAD + 255) / 256, 256, 0, stream>>>(fs, al2, ar2, el, er, N_NODES);
  edge_agg_kernel<false><<<(N_NODES * 64 + 255) / 256, 256, 0, stream>>>(
      rowstart, esrc, el, er, fs, b2, h2, N_NODES);

  // readout
  pool_sum_kernel<<<((N_NODES + 63) / 64 * 64 + 255) / 256, 256, 0, stream>>>(h2, n2g, hg, N_NODES);
  classifier_kernel<<<(N_GRAPHS * NC + 255) / 256, 256, 0, stream>>>(hg, gstart, Wc, bc, out);
}

// Round 4
// 564.242 us; speedup vs baseline: 1.3930x; 1.1019x over previous
//
#include <hip/hip_runtime.h>
#include <hip/hip_bf16.h>

#define N_NODES 50000
#define N_EDGES 500000
#define N_GRAPHS 64
#define FDIM 256   // H*HID
#define NHEAD 8
#define NC 10
#define SLOPE 0.2f
#define MPAD 50048  // N_NODES rounded up to 64

typedef __attribute__((ext_vector_type(8))) short bf16x8;
typedef __attribute__((ext_vector_type(4))) float f32x4;

__device__ __forceinline__ unsigned short f2bf(float f) {
  unsigned x = __float_as_uint(f);
  x += 0x7fff + ((x >> 16) & 1);   // RNE
  return (unsigned short)(x >> 16);
}

// ---------------- CSR build ----------------
__global__ void hist_kernel(const int* __restrict__ dst, int* __restrict__ deg, int E) {
  int e = blockIdx.x * blockDim.x + threadIdx.x;
  if (e < E) atomicAdd(&deg[dst[e]], 1);
}

// single-block exclusive scan of deg[0..n) -> rowstart[0..n]
__global__ void scan_kernel(const int* __restrict__ deg, int* __restrict__ rowstart, int n) {
  __shared__ int wsum[16];
  __shared__ int carry_s;
  int t = threadIdx.x, lane = t & 63, w = t >> 6;
  if (t == 0) carry_s = 0;
  __syncthreads();
  for (int base = 0; base < n; base += 1024) {
    int i = base + t;
    int v = (i < n) ? deg[i] : 0;
    int x = v;
    #pragma unroll
    for (int off = 1; off < 64; off <<= 1) {
      int y = __shfl_up(x, off);
      if (lane >= off) x += y;
    }
    if (lane == 63) wsum[w] = x;
    __syncthreads();
    if (w == 0 && lane < 16) {
      int s = wsum[lane];
      #pragma unroll
      for (int off = 1; off < 16; off <<= 1) {
        int y = __shfl_up(s, off);
        if (lane >= off) s += y;
      }
      wsum[lane] = s;  // inclusive over wave sums
    }
    __syncthreads();
    int woff = (w > 0) ? wsum[w - 1] : 0;
    int incl = x + woff;
    int carry = carry_s;
    if (i < n) rowstart[i] = carry + incl - v;
    __syncthreads();
    if (t == 1023) carry_s = carry + incl;
    __syncthreads();
  }
  if (t == 0) rowstart[n] = carry_s;
}

__global__ void scatter_kernel(const int* __restrict__ src, const int* __restrict__ dst,
                               const int* __restrict__ rowstart, int* __restrict__ cursor,
                               int* __restrict__ esrc, int E) {
  int e = blockIdx.x * blockDim.x + threadIdx.x;
  if (e >= E) return;
  int d = dst[e];
  int p = atomicAdd(&cursor[d], 1);
  esrc[rowstart[d] + p] = src[e];
}

// per-graph node ranges (node2graph is sorted)
__global__ void graph_bounds_kernel(const int* __restrict__ n2g, int* __restrict__ gstart,
                                    int n, int ngraph) {
  int i = blockIdx.x * blockDim.x + threadIdx.x;
  if (i >= n) return;
  int g1 = n2g[i];
  int g0 = (i == 0) ? -1 : n2g[i - 1];
  for (int g = g0 + 1; g <= g1; ++g) gstart[g] = i;
  if (i == n - 1) {
    for (int g = g1 + 1; g <= ngraph; ++g) gstart[g] = n;
  }
}

// ---------------- casts ----------------
// fp32 -> bf16, 4 elems/thread
__global__ void cast_bf16_kernel(const float* __restrict__ src, unsigned short* __restrict__ dst,
                                 int n4) {
  int i = blockIdx.x * blockDim.x + threadIdx.x;
  if (i >= n4) return;
  float4 v = *(const float4*)(src + (size_t)i * 4);
  ushort4 o;
  o.x = f2bf(v.x); o.y = f2bf(v.y); o.z = f2bf(v.z); o.w = f2bf(v.w);
  *(ushort4*)(dst + (size_t)i * 4) = o;
}

// W[K][256] fp32 -> Wt[256][K] bf16 (n-major, k contiguous)
template<int K>
__global__ void castT_kernel(const float* __restrict__ W, unsigned short* __restrict__ Wt) {
  int tid = blockIdx.x * blockDim.x + threadIdx.x;
  if (tid >= 256 * K) return;
  int n = tid / K, k = tid % K;
  Wt[(size_t)n * K + k] = f2bf(W[(size_t)k * 256 + n]);
}

// ---------------- MFMA GEMM: C[nrows,256](f32) = A[nrows,K](bf16) @ Wt^T ----------------
// Wt is [256][K] bf16 (n-major). Block = 256 thr (4 waves), 64-row tile, no LDS.
// Per wave: one 16-row stripe x 16 col-tiles of 16, mfma_f32_16x16x32_bf16.
template<int K>
__global__ void gemm_mfma(const unsigned short* __restrict__ A,
                          const unsigned short* __restrict__ Wt,
                          float* __restrict__ C, int nrows) {
  int lane = threadIdx.x & 63;
  int wave = threadIdx.x >> 6;
  int row0 = blockIdx.x * 64 + wave * 16;
  int m = lane & 15;
  int q = lane >> 4;           // 0..3
  const unsigned short* arow = A + (size_t)(row0 + m) * K + q * 8;
  f32x4 acc[16];
  #pragma unroll
  for (int nt = 0; nt < 16; ++nt) acc[nt] = (f32x4){0.f, 0.f, 0.f, 0.f};
  for (int kc = 0; kc < K; kc += 32) {
    bf16x8 af = *(const bf16x8*)(arow + kc);
    #pragma unroll
    for (int nt = 0; nt < 16; ++nt) {
      bf16x8 bfv = *(const bf16x8*)(Wt + (size_t)(nt * 16 + m) * K + kc + q * 8);
      acc[nt] = __builtin_amdgcn_mfma_f32_16x16x32_bf16(af, bfv, acc[nt], 0, 0, 0);
    }
  }
  // C/D layout: col = lane&15, row = q*4 + reg   [verified m89/m91]
  int crow = row0 + q * 4;
  if (crow + 3 < nrows) {
    #pragma unroll
    for (int nt = 0; nt < 16; ++nt) {
      #pragma unroll
      for (int i = 0; i < 4; ++i)
        C[(size_t)(crow + i) * 256 + nt * 16 + m] = acc[nt][i];
    }
  } else {
    #pragma unroll
    for (int nt = 0; nt < 16; ++nt) {
      #pragma unroll
      for (int i = 0; i < 4; ++i)
        if (crow + i < nrows) C[(size_t)(crow + i) * 256 + nt * 16 + m] = acc[nt][i];
    }
  }
}

// ---------------- attention logits el/er ----------------
__global__ void elr_kernel(const float* __restrict__ fs, const float* __restrict__ al,
                           const float* __restrict__ ar, float* __restrict__ el,
                           float* __restrict__ er, int nnodes) {
  int tid = blockIdx.x * blockDim.x + threadIdx.x;
  if (tid >= nnodes * NHEAD) return;
  int n = tid >> 3, h = tid & 7;
  const float4* f = (const float4*)&fs[(size_t)n * FDIM + h * 32];
  const float4* a4 = (const float4*)(al + h * 32);
  const float4* r4 = (const float4*)(ar + h * 32);
  float sl = 0.f, sr = 0.f;
  #pragma unroll
  for (int i = 0; i < 8; ++i) {
    float4 v = f[i];
    float4 a = a4[i];
    float4 r = r4[i];
    sl += v.x * a.x + v.y * a.y + v.z * a.z + v.w * a.w;
    sr += v.x * r.x + v.y * r.y + v.z * r.z + v.w * r.w;
  }
  el[tid] = sl;
  er[tid] = sr;
}

// ---------------- edge softmax + message aggregation: one wave per dst node ----------------
// lane l handles output elements 4l..4l+3  (head h = l>>3)
template<bool RELU, bool BF16OUT>
__global__ void edge_agg_kernel(const int* __restrict__ rowstart, const int* __restrict__ esrc,
                                const float* __restrict__ el, const float* __restrict__ er,
                                const float* __restrict__ fs, const float* __restrict__ bias,
                                void* __restrict__ out, int nnodes) {
  int gid = blockIdx.x * blockDim.x + threadIdx.x;
  int v = gid >> 6;
  int lane = threadIdx.x & 63;
  if (v >= nnodes) return;
  int h = lane >> 3;
  int row0 = rowstart[v];
  int deg = rowstart[v + 1] - row0;
  float er_vh = er[v * NHEAD + h];
  // phase 1: softmax denominator per head (8 lanes per head split the edges)
  float psum = 0.f;
  for (int j = lane & 7; j < deg; j += 8) {
    int s = esrc[row0 + j];
    float x = el[s * NHEAD + h] + er_vh;
    x = (x >= 0.f) ? x : SLOPE * x;
    psum += __expf(x);
  }
  psum += __shfl_xor(psum, 1);
  psum += __shfl_xor(psum, 2);
  psum += __shfl_xor(psum, 4);
  float rdenom = (deg > 0) ? (1.0f / psum) : 0.f;
  // phase 2: weighted gather of fs[src]
  float4 acc = make_float4(0.f, 0.f, 0.f, 0.f);
  for (int j = 0; j < deg; ++j) {
    int s = esrc[row0 + j];
    float x = el[s * NHEAD + h] + er_vh;
    x = (x >= 0.f) ? x : SLOPE * x;
    float wgt = __expf(x) * rdenom;
    float4 f = *(const float4*)&fs[(size_t)s * FDIM + lane * 4];
    acc.x = fmaf(wgt, f.x, acc.x);
    acc.y = fmaf(wgt, f.y, acc.y);
    acc.z = fmaf(wgt, f.z, acc.z);
    acc.w = fmaf(wgt, f.w, acc.w);
  }
  const float4 b = *(const float4*)(bias + lane * 4);
  acc.x += b.x; acc.y += b.y; acc.z += b.z; acc.w += b.w;
  if (RELU) {
    acc.x = fmaxf(acc.x, 0.f); acc.y = fmaxf(acc.y, 0.f);
    acc.z = fmaxf(acc.z, 0.f); acc.w = fmaxf(acc.w, 0.f);
  }
  if (BF16OUT) {
    ushort4 o;
    o.x = f2bf(acc.x); o.y = f2bf(acc.y); o.z = f2bf(acc.z); o.w = f2bf(acc.w);
    *(ushort4*)((unsigned short*)out + (size_t)v * FDIM + lane * 4) = o;
  } else {
    *(float4*)((float*)out + (size_t)v * FDIM + lane * 4) = acc;
  }
}

// ---------------- per-graph sum pool (node-parallel, register-accumulated) ----------------
__global__ void pool_sum_kernel(const float* __restrict__ h2, const int* __restrict__ n2g,
                                float* __restrict__ hg, int nnodes) {
  int wave = (blockIdx.x * blockDim.x + threadIdx.x) >> 6;
  int lane = threadIdx.x & 63;
  int n0 = wave * 64;
  if (n0 >= nnodes) return;
  int n1 = min(n0 + 64, nnodes);
  int curg = n2g[n0];
  float4 acc = make_float4(0.f, 0.f, 0.f, 0.f);
  for (int n = n0; n < n1; ++n) {
    int g = n2g[n];
    if (g != curg) {
      float* p = &hg[(size_t)curg * FDIM + lane * 4];
      atomicAdd(p + 0, acc.x); atomicAdd(p + 1, acc.y);
      atomicAdd(p + 2, acc.z); atomicAdd(p + 3, acc.w);
      acc = make_float4(0.f, 0.f, 0.f, 0.f);
      curg = g;
    }
    float4 v = *(const float4*)&h2[(size_t)n * FDIM + lane * 4];
    acc.x += v.x; acc.y += v.y; acc.z += v.z; acc.w += v.w;
  }
  float* p = &hg[(size_t)curg * FDIM + lane * 4];
  atomicAdd(p + 0, acc.x); atomicAdd(p + 1, acc.y);
  atomicAdd(p + 2, acc.z); atomicAdd(p + 3, acc.w);
}

// ---------------- classifier (divides pooled sums by per-graph count) ----------------
__global__ void classifier_kernel(const float* __restrict__ hgsum, const int* __restrict__ gstart,
                                  const float* __restrict__ Wc, const float* __restrict__ bcv,
                                  float* __restrict__ out) {
  int tid = blockIdx.x * blockDim.x + threadIdx.x;
  if (tid >= N_GRAPHS * NC) return;
  int b = tid / NC, j = tid % NC;
  int cnt = gstart[b + 1] - gstart[b];
  float inv = (cnt > 0) ? (1.0f / (float)cnt) : 1.0f;
  float s = 0.f;
  for (int c = 0; c < FDIM; ++c) s += hgsum[b * FDIM + c] * Wc[c * NC + j];
  out[tid] = s * inv + bcv[j];
}

extern "C" void kernel_launch(void* const* d_in, const int* in_sizes, int n_in,
                              void* d_out, int out_size, void* d_ws, size_t ws_size,
                              hipStream_t stream) {
  const float* feat = (const float*)d_in[0];
  const int* src    = (const int*)d_in[1];
  const int* dst    = (const int*)d_in[2];
  const int* n2g    = (const int*)d_in[3];
  const float* W1  = (const float*)d_in[4];
  const float* al1 = (const float*)d_in[5];
  const float* ar1 = (const float*)d_in[6];
  const float* b1  = (const float*)d_in[7];
  const float* W2  = (const float*)d_in[8];
  const float* al2 = (const float*)d_in[9];
  const float* ar2 = (const float*)d_in[10];
  const float* b2  = (const float*)d_in[11];
  const float* Wc  = (const float*)d_in[12];
  const float* bc  = (const float*)d_in[13];
  float* out = (float*)d_out;

  char* wp = (char*)d_ws;
  auto carve = [&](size_t bytes) -> void* {
    void* p = (void*)wp;
    wp += (bytes + 255) & ~(size_t)255;
    return p;
  };
  float* fs = (float*)carve((size_t)N_NODES * FDIM * 4);   // 51.2 MB
  // region R1 (51.2 MB): A1_bf + h1_bf live first, then h2 overwrites both
  char* R1  = (char*)carve((size_t)N_NODES * FDIM * 4);
  unsigned short* A1 = (unsigned short*)R1;                          // [MPAD][128] bf16, 12.8 MB
  unsigned short* h1 = (unsigned short*)(R1 + (size_t)MPAD * 128 * 2); // [MPAD][256] bf16, 25.6 MB
  float* h2 = (float*)R1;                                            // [N][256] f32 after h1 dead
  unsigned short* Wt1 = (unsigned short*)carve((size_t)256 * 128 * 2);
  unsigned short* Wt2 = (unsigned short*)carve((size_t)256 * 256 * 2);
  float* el      = (float*)carve((size_t)N_NODES * NHEAD * 4);
  float* er      = (float*)carve((size_t)N_NODES * NHEAD * 4);
  int* rowstart  = (int*)  carve((size_t)(N_NODES + 1) * 4);
  int* cursor    = (int*)  carve((size_t)N_NODES * 4);
  int* esrc      = (int*)  carve((size_t)N_EDGES * 4);
  int* gstart    = (int*)  carve((size_t)(N_GRAPHS + 1) * 4);
  float* hg      = (float*)carve((size_t)N_GRAPHS * FDIM * 4);
  (void)ws_size; (void)n_in; (void)in_sizes; (void)out_size;

  // CSR build + weight prep
  hipMemsetAsync(cursor, 0, (size_t)N_NODES * 4, stream);
  hipMemsetAsync(hg, 0, (size_t)N_GRAPHS * FDIM * 4, stream);
  hist_kernel<<<(N_EDGES + 255) / 256, 256, 0, stream>>>(dst, cursor, N_EDGES);
  scan_kernel<<<1, 1024, 0, stream>>>(cursor, rowstart, N_NODES);
  hipMemsetAsync(cursor, 0, (size_t)N_NODES * 4, stream);
  scatter_kernel<<<(N_EDGES + 255) / 256, 256, 0, stream>>>(src, dst, rowstart, cursor, esrc, N_EDGES);
  graph_bounds_kernel<<<(N_NODES + 255) / 256, 256, 0, stream>>>(n2g, gstart, N_NODES, N_GRAPHS);
  castT_kernel<128><<<(256 * 128 + 255) / 256, 256, 0, stream>>>(W1, Wt1);
  castT_kernel<256><<<(256 * 256 + 255) / 256, 256, 0, stream>>>(W2, Wt2);
  cast_bf16_kernel<<<(N_NODES * 128 / 4 + 255) / 256, 256, 0, stream>>>(feat, A1, N_NODES * 128 / 4);

  // layer 1
  gemm_mfma<128><<<(N_NODES + 63) / 64, 256, 0, stream>>>(A1, Wt1, fs, N_NODES);
  elr_kernel<<<(N_NODES * NHEAD + 255) / 256, 256, 0, stream>>>(fs, al1, ar1, el, er, N_NODES);
  edge_agg_kernel<true, true><<<(N_NODES * 64 + 255) / 256, 256, 0, stream>>>(
      rowstart, esrc, el, er, fs, b1, (void*)h1, N_NODES);

  // layer 2
  gemm_mfma<256><<<(N_NODES + 63) / 64, 256, 0, stream>>>(h1, Wt2, fs, N_NODES);
  elr_kernel<<<(N_NODES * NHEAD + 255) / 256, 256, 0, stream>>>(fs, al2, ar2, el, er, N_NODES);
  edge_agg_kernel<false, false><<<(N_NODES * 64 + 255) / 256, 256, 0, stream>>>(
      rowstart, esrc, el, er, fs, b2, (void*)h2, N_NODES);

  // readout
  pool_sum_kernel<<<((N_NODES + 63) / 64 * 64 + 255) / 256, 256, 0, stream>>>(h2, n2g, hg, N_NODES);
  classifier_kernel<<<(N_GRAPHS * NC + 255) / 256, 256, 0, stream>>>(hg, gstart, Wc, bc, out);
}

// Round 5
// 470.482 us; speedup vs baseline: 1.6706x; 1.1993x over previous
//
#include <hip/hip_runtime.h>
#include <hip/hip_bf16.h>

#define N_NODES 50000
#define N_EDGES 500000
#define N_GRAPHS 64
#define FDIM 256   // H*HID
#define NHEAD 8
#define NC 10
#define SLOPE 0.2f
#define MPAD 50048  // N_NODES rounded up to 64

typedef __attribute__((ext_vector_type(8))) short bf16x8;
typedef __attribute__((ext_vector_type(4))) float f32x4;

__device__ __forceinline__ unsigned short f2bf(float f) {
  unsigned x = __float_as_uint(f);
  x += 0x7fff + ((x >> 16) & 1);   // RNE
  return (unsigned short)(x >> 16);
}
__device__ __forceinline__ float b2f(unsigned short u) {
  return __uint_as_float((unsigned)u << 16);
}

// ---------------- CSR build ----------------
__global__ void hist_kernel(const int* __restrict__ dst, int* __restrict__ deg, int E) {
  int e = blockIdx.x * blockDim.x + threadIdx.x;
  if (e < E) atomicAdd(&deg[dst[e]], 1);
}

// single-block exclusive scan of deg[0..n) -> rowstart[0..n]
__global__ void scan_kernel(const int* __restrict__ deg, int* __restrict__ rowstart, int n) {
  __shared__ int wsum[16];
  __shared__ int carry_s;
  int t = threadIdx.x, lane = t & 63, w = t >> 6;
  if (t == 0) carry_s = 0;
  __syncthreads();
  for (int base = 0; base < n; base += 1024) {
    int i = base + t;
    int v = (i < n) ? deg[i] : 0;
    int x = v;
    #pragma unroll
    for (int off = 1; off < 64; off <<= 1) {
      int y = __shfl_up(x, off);
      if (lane >= off) x += y;
    }
    if (lane == 63) wsum[w] = x;
    __syncthreads();
    if (w == 0 && lane < 16) {
      int s = wsum[lane];
      #pragma unroll
      for (int off = 1; off < 16; off <<= 1) {
        int y = __shfl_up(s, off);
        if (lane >= off) s += y;
      }
      wsum[lane] = s;  // inclusive over wave sums
    }
    __syncthreads();
    int woff = (w > 0) ? wsum[w - 1] : 0;
    int incl = x + woff;
    int carry = carry_s;
    if (i < n) rowstart[i] = carry + incl - v;
    __syncthreads();
    if (t == 1023) carry_s = carry + incl;
    __syncthreads();
  }
  if (t == 0) rowstart[n] = carry_s;
}

__global__ void scatter_kernel(const int* __restrict__ src, const int* __restrict__ dst,
                               const int* __restrict__ rowstart, int* __restrict__ cursor,
                               int* __restrict__ esrc, int E) {
  int e = blockIdx.x * blockDim.x + threadIdx.x;
  if (e >= E) return;
  int d = dst[e];
  int p = atomicAdd(&cursor[d], 1);
  esrc[rowstart[d] + p] = src[e];
}

// per-graph node ranges (node2graph is sorted)
__global__ void graph_bounds_kernel(const int* __restrict__ n2g, int* __restrict__ gstart,
                                    int n, int ngraph) {
  int i = blockIdx.x * blockDim.x + threadIdx.x;
  if (i >= n) return;
  int g1 = n2g[i];
  int g0 = (i == 0) ? -1 : n2g[i - 1];
  for (int g = g0 + 1; g <= g1; ++g) gstart[g] = i;
  if (i == n - 1) {
    for (int g = g1 + 1; g <= ngraph; ++g) gstart[g] = n;
  }
}

// ---------------- casts ----------------
__global__ void cast_bf16_kernel(const float* __restrict__ src, unsigned short* __restrict__ dst,
                                 int n4) {
  int i = blockIdx.x * blockDim.x + threadIdx.x;
  if (i >= n4) return;
  float4 v = *(const float4*)(src + (size_t)i * 4);
  ushort4 o;
  o.x = f2bf(v.x); o.y = f2bf(v.y); o.z = f2bf(v.z); o.w = f2bf(v.w);
  *(ushort4*)(dst + (size_t)i * 4) = o;
}

// W[K][256] fp32 -> Wt[256][K] bf16 (n-major, k contiguous)
template<int K>
__global__ void castT_kernel(const float* __restrict__ W, unsigned short* __restrict__ Wt) {
  int tid = blockIdx.x * blockDim.x + threadIdx.x;
  if (tid >= 256 * K) return;
  int n = tid / K, k = tid % K;
  Wt[(size_t)n * K + k] = f2bf(W[(size_t)k * 256 + n]);
}

// ---------------- MFMA GEMM: C[nrows,256](bf16) = A[nrows,K](bf16) @ Wt^T ----------------
// Wt is [256][K] bf16 (n-major). Block = 256 thr (4 waves), 64-row tile, no LDS.
template<int K>
__global__ void gemm_mfma(const unsigned short* __restrict__ A,
                          const unsigned short* __restrict__ Wt,
                          unsigned short* __restrict__ C, int nrows) {
  int lane = threadIdx.x & 63;
  int wave = threadIdx.x >> 6;
  int row0 = blockIdx.x * 64 + wave * 16;
  int m = lane & 15;
  int q = lane >> 4;           // 0..3
  const unsigned short* arow = A + (size_t)(row0 + m) * K + q * 8;
  f32x4 acc[16];
  #pragma unroll
  for (int nt = 0; nt < 16; ++nt) acc[nt] = (f32x4){0.f, 0.f, 0.f, 0.f};
  for (int kc = 0; kc < K; kc += 32) {
    bf16x8 af = *(const bf16x8*)(arow + kc);
    #pragma unroll
    for (int nt = 0; nt < 16; ++nt) {
      bf16x8 bfv = *(const bf16x8*)(Wt + (size_t)(nt * 16 + m) * K + kc + q * 8);
      acc[nt] = __builtin_amdgcn_mfma_f32_16x16x32_bf16(af, bfv, acc[nt], 0, 0, 0);
    }
  }
  // C/D layout: col = lane&15, row = q*4 + reg   [verified m89/m91]
  int crow = row0 + q * 4;
  #pragma unroll
  for (int nt = 0; nt < 16; ++nt) {
    #pragma unroll
    for (int i = 0; i < 4; ++i)
      if (crow + i < nrows) C[(size_t)(crow + i) * 256 + nt * 16 + m] = f2bf(acc[nt][i]);
  }
}

// ---------------- attention logits el/er (bf16 fs) ----------------
__global__ void elr_kernel(const unsigned short* __restrict__ fs, const float* __restrict__ al,
                           const float* __restrict__ ar, float* __restrict__ el,
                           float* __restrict__ er, int nnodes) {
  int tid = blockIdx.x * blockDim.x + threadIdx.x;
  if (tid >= nnodes * NHEAD) return;
  int n = tid >> 3, h = tid & 7;
  const ushort4* f = (const ushort4*)&fs[(size_t)n * FDIM + h * 32];
  const float4* a4 = (const float4*)(al + h * 32);
  const float4* r4 = (const float4*)(ar + h * 32);
  float sl = 0.f, sr = 0.f;
  #pragma unroll
  for (int i = 0; i < 8; ++i) {
    ushort4 u = f[i];
    float4 a = a4[i];
    float4 r = r4[i];
    float vx = b2f(u.x), vy = b2f(u.y), vz = b2f(u.z), vw = b2f(u.w);
    sl += vx * a.x + vy * a.y + vz * a.z + vw * a.w;
    sr += vx * r.x + vy * r.y + vz * r.z + vw * r.w;
  }
  el[tid] = sl;
  er[tid] = sr;
}

// ---------------- fused edge softmax + aggregation: one wave per dst node ----------------
// single pass: acc = sum_j w_j * fs[s_j], wsum = sum_j w_j; out = acc/wsum + b.
// lane l handles channels 4l..4l+3 (head h = l>>3); 1-deep prefetch pipeline.
template<bool RELU, bool BF16OUT>
__global__ void edge_agg_kernel(const int* __restrict__ rowstart, const int* __restrict__ esrc,
                                const float* __restrict__ el, const float* __restrict__ er,
                                const unsigned short* __restrict__ fs,
                                const float* __restrict__ bias,
                                void* __restrict__ out, int nnodes) {
  int gid = blockIdx.x * blockDim.x + threadIdx.x;
  int v = gid >> 6;
  int lane = threadIdx.x & 63;
  if (v >= nnodes) return;
  int h = lane >> 3;
  int row0 = rowstart[v];
  int deg = rowstart[v + 1] - row0;
  float er_vh = er[v * NHEAD + h];
  float4 acc = make_float4(0.f, 0.f, 0.f, 0.f);
  float wsum = 0.f;
  if (deg > 0) {
    int s = esrc[row0];
    float elv = el[s * NHEAD + h];
    ushort4 f = *(const ushort4*)&fs[(size_t)s * FDIM + lane * 4];
    for (int j = 0; j < deg - 1; ++j) {
      int s2 = esrc[row0 + j + 1];
      float elv2 = el[s2 * NHEAD + h];
      ushort4 f2 = *(const ushort4*)&fs[(size_t)s2 * FDIM + lane * 4];
      float x = elv + er_vh;
      x = (x >= 0.f) ? x : SLOPE * x;
      float w = __expf(x);
      wsum += w;
      acc.x = fmaf(w, b2f(f.x), acc.x);
      acc.y = fmaf(w, b2f(f.y), acc.y);
      acc.z = fmaf(w, b2f(f.z), acc.z);
      acc.w = fmaf(w, b2f(f.w), acc.w);
      s = s2; elv = elv2; f = f2;
    }
    float x = elv + er_vh;
    x = (x >= 0.f) ? x : SLOPE * x;
    float w = __expf(x);
    wsum += w;
    acc.x = fmaf(w, b2f(f.x), acc.x);
    acc.y = fmaf(w, b2f(f.y), acc.y);
    acc.z = fmaf(w, b2f(f.z), acc.z);
    acc.w = fmaf(w, b2f(f.w), acc.w);
  }
  float rdenom = (deg > 0) ? (1.0f / wsum) : 0.f;
  const float4 b = *(const float4*)(bias + lane * 4);
  acc.x = fmaf(acc.x, rdenom, b.x);
  acc.y = fmaf(acc.y, rdenom, b.y);
  acc.z = fmaf(acc.z, rdenom, b.z);
  acc.w = fmaf(acc.w, rdenom, b.w);
  if (RELU) {
    acc.x = fmaxf(acc.x, 0.f); acc.y = fmaxf(acc.y, 0.f);
    acc.z = fmaxf(acc.z, 0.f); acc.w = fmaxf(acc.w, 0.f);
  }
  if (BF16OUT) {
    ushort4 o;
    o.x = f2bf(acc.x); o.y = f2bf(acc.y); o.z = f2bf(acc.z); o.w = f2bf(acc.w);
    *(ushort4*)((unsigned short*)out + (size_t)v * FDIM + lane * 4) = o;
  } else {
    *(float4*)((float*)out + (size_t)v * FDIM + lane * 4) = acc;
  }
}

// ---------------- per-graph sum pool (node-parallel, register-accumulated) ----------------
__global__ void pool_sum_kernel(const float* __restrict__ h2, const int* __restrict__ n2g,
                                float* __restrict__ hg, int nnodes) {
  int wave = (blockIdx.x * blockDim.x + threadIdx.x) >> 6;
  int lane = threadIdx.x & 63;
  int n0 = wave * 64;
  if (n0 >= nnodes) return;
  int n1 = min(n0 + 64, nnodes);
  int curg = n2g[n0];
  float4 acc = make_float4(0.f, 0.f, 0.f, 0.f);
  for (int n = n0; n < n1; ++n) {
    int g = n2g[n];
    if (g != curg) {
      float* p = &hg[(size_t)curg * FDIM + lane * 4];
      atomicAdd(p + 0, acc.x); atomicAdd(p + 1, acc.y);
      atomicAdd(p + 2, acc.z); atomicAdd(p + 3, acc.w);
      acc = make_float4(0.f, 0.f, 0.f, 0.f);
      curg = g;
    }
    float4 v = *(const float4*)&h2[(size_t)n * FDIM + lane * 4];
    acc.x += v.x; acc.y += v.y; acc.z += v.z; acc.w += v.w;
  }
  float* p = &hg[(size_t)curg * FDIM + lane * 4];
  atomicAdd(p + 0, acc.x); atomicAdd(p + 1, acc.y);
  atomicAdd(p + 2, acc.z); atomicAdd(p + 3, acc.w);
}

// ---------------- classifier (divides pooled sums by per-graph count) ----------------
__global__ void classifier_kernel(const float* __restrict__ hgsum, const int* __restrict__ gstart,
                                  const float* __restrict__ Wc, const float* __restrict__ bcv,
                                  float* __restrict__ out) {
  int tid = blockIdx.x * blockDim.x + threadIdx.x;
  if (tid >= N_GRAPHS * NC) return;
  int b = tid / NC, j = tid % NC;
  int cnt = gstart[b + 1] - gstart[b];
  float inv = (cnt > 0) ? (1.0f / (float)cnt) : 1.0f;
  float s = 0.f;
  for (int c = 0; c < FDIM; ++c) s += hgsum[b * FDIM + c] * Wc[c * NC + j];
  out[tid] = s * inv + bcv[j];
}

extern "C" void kernel_launch(void* const* d_in, const int* in_sizes, int n_in,
                              void* d_out, int out_size, void* d_ws, size_t ws_size,
                              hipStream_t stream) {
  const float* feat = (const float*)d_in[0];
  const int* src    = (const int*)d_in[1];
  const int* dst    = (const int*)d_in[2];
  const int* n2g    = (const int*)d_in[3];
  const float* W1  = (const float*)d_in[4];
  const float* al1 = (const float*)d_in[5];
  const float* ar1 = (const float*)d_in[6];
  const float* b1  = (const float*)d_in[7];
  const float* W2  = (const float*)d_in[8];
  const float* al2 = (const float*)d_in[9];
  const float* ar2 = (const float*)d_in[10];
  const float* b2  = (const float*)d_in[11];
  const float* Wc  = (const float*)d_in[12];
  const float* bc  = (const float*)d_in[13];
  float* out = (float*)d_out;

  char* wp = (char*)d_ws;
  auto carve = [&](size_t bytes) -> void* {
    void* p = (void*)wp;
    wp += (bytes + 255) & ~(size_t)255;
    return p;
  };
  unsigned short* fs = (unsigned short*)carve((size_t)N_NODES * FDIM * 2);  // 25.6 MB bf16
  // region R1 (51.2 MB): A1_bf + h1_bf live first, then h2(f32) overwrites both
  char* R1  = (char*)carve((size_t)N_NODES * FDIM * 4);
  unsigned short* A1 = (unsigned short*)R1;                            // [MPAD][128] bf16
  unsigned short* h1 = (unsigned short*)(R1 + (size_t)MPAD * 128 * 2); // [MPAD][256] bf16
  float* h2 = (float*)R1;                                              // [N][256] f32 after h1 dead
  unsigned short* Wt1 = (unsigned short*)carve((size_t)256 * 128 * 2);
  unsigned short* Wt2 = (unsigned short*)carve((size_t)256 * 256 * 2);
  float* el      = (float*)carve((size_t)N_NODES * NHEAD * 4);
  float* er      = (float*)carve((size_t)N_NODES * NHEAD * 4);
  int* rowstart  = (int*)  carve((size_t)(N_NODES + 1) * 4);
  int* cursor    = (int*)  carve((size_t)N_NODES * 4);
  int* esrc      = (int*)  carve((size_t)N_EDGES * 4);
  int* gstart    = (int*)  carve((size_t)(N_GRAPHS + 1) * 4);
  float* hg      = (float*)carve((size_t)N_GRAPHS * FDIM * 4);
  (void)ws_size; (void)n_in; (void)in_sizes; (void)out_size;

  // CSR build + weight prep
  hipMemsetAsync(cursor, 0, (size_t)N_NODES * 4, stream);
  hipMemsetAsync(hg, 0, (size_t)N_GRAPHS * FDIM * 4, stream);
  hist_kernel<<<(N_EDGES + 255) / 256, 256, 0, stream>>>(dst, cursor, N_EDGES);
  scan_kernel<<<1, 1024, 0, stream>>>(cursor, rowstart, N_NODES);
  hipMemsetAsync(cursor, 0, (size_t)N_NODES * 4, stream);
  scatter_kernel<<<(N_EDGES + 255) / 256, 256, 0, stream>>>(src, dst, rowstart, cursor, esrc, N_EDGES);
  graph_bounds_kernel<<<(N_NODES + 255) / 256, 256, 0, stream>>>(n2g, gstart, N_NODES, N_GRAPHS);
  castT_kernel<128><<<(256 * 128 + 255) / 256, 256, 0, stream>>>(W1, Wt1);
  castT_kernel<256><<<(256 * 256 + 255) / 256, 256, 0, stream>>>(W2, Wt2);
  cast_bf16_kernel<<<(N_NODES * 128 / 4 + 255) / 256, 256, 0, stream>>>(feat, A1, N_NODES * 128 / 4);

  // layer 1
  gemm_mfma<128><<<(N_NODES + 63) / 64, 256, 0, stream>>>(A1, Wt1, fs, N_NODES);
  elr_kernel<<<(N_NODES * NHEAD + 255) / 256, 256, 0, stream>>>(fs, al1, ar1, el, er, N_NODES);
  edge_agg_kernel<true, true><<<(N_NODES * 64 + 255) / 256, 256, 0, stream>>>(
      rowstart, esrc, el, er, fs, b1, (void*)h1, N_NODES);

  // layer 2
  gemm_mfma<256><<<(N_NODES + 63) / 64, 256, 0, stream>>>(h1, Wt2, fs, N_NODES);
  elr_kernel<<<(N_NODES * NHEAD + 255) / 256, 256, 0, stream>>>(fs, al2, ar2, el, er, N_NODES);
  edge_agg_kernel<false, false><<<(N_NODES * 64 + 255) / 256, 256, 0, stream>>>(
      rowstart, esrc, el, er, fs, b2, (void*)h2, N_NODES);

  // readout
  pool_sum_kernel<<<((N_NODES + 63) / 64 * 64 + 255) / 256, 256, 0, stream>>>(h2, n2g, hg, N_NODES);
  classifier_kernel<<<(N_GRAPHS * NC + 255) / 256, 256, 0, stream>>>(hg, gstart, Wc, bc, out);
}

// Round 6
// 455.847 us; speedup vs baseline: 1.7242x; 1.0321x over previous
//
#include <hip/hip_runtime.h>
#include <hip/hip_bf16.h>

#define N_NODES 50000
#define N_EDGES 500000
#define N_GRAPHS 64
#define FDIM 256   // H*HID
#define NHEAD 8
#define NC 10
#define SLOPE 0.2f
#define MPAD 50048  // N_NODES rounded up to 64

typedef __attribute__((ext_vector_type(8))) short bf16x8;
typedef __attribute__((ext_vector_type(4))) float f32x4;

__device__ __forceinline__ unsigned short f2bf(float f) {
  unsigned x = __float_as_uint(f);
  x += 0x7fff + ((x >> 16) & 1);   // RNE
  return (unsigned short)(x >> 16);
}
__device__ __forceinline__ float b2f(unsigned short u) {
  return __uint_as_float((unsigned)u << 16);
}

// ---------------- CSR build ----------------
__global__ void hist_kernel(const int* __restrict__ dst, int* __restrict__ deg, int E) {
  int e = blockIdx.x * blockDim.x + threadIdx.x;
  if (e < E) atomicAdd(&deg[dst[e]], 1);
}

// single-block exclusive scan of deg[0..n) -> rowstart[0..n]
__global__ void scan_kernel(const int* __restrict__ deg, int* __restrict__ rowstart, int n) {
  __shared__ int wsum[16];
  __shared__ int carry_s;
  int t = threadIdx.x, lane = t & 63, w = t >> 6;
  if (t == 0) carry_s = 0;
  __syncthreads();
  for (int base = 0; base < n; base += 1024) {
    int i = base + t;
    int v = (i < n) ? deg[i] : 0;
    int x = v;
    #pragma unroll
    for (int off = 1; off < 64; off <<= 1) {
      int y = __shfl_up(x, off);
      if (lane >= off) x += y;
    }
    if (lane == 63) wsum[w] = x;
    __syncthreads();
    if (w == 0 && lane < 16) {
      int s = wsum[lane];
      #pragma unroll
      for (int off = 1; off < 16; off <<= 1) {
        int y = __shfl_up(s, off);
        if (lane >= off) s += y;
      }
      wsum[lane] = s;  // inclusive over wave sums
    }
    __syncthreads();
    int woff = (w > 0) ? wsum[w - 1] : 0;
    int incl = x + woff;
    int carry = carry_s;
    if (i < n) rowstart[i] = carry + incl - v;
    __syncthreads();
    if (t == 1023) carry_s = carry + incl;
    __syncthreads();
  }
  if (t == 0) rowstart[n] = carry_s;
}

__global__ void scatter_kernel(const int* __restrict__ src, const int* __restrict__ dst,
                               const int* __restrict__ rowstart, int* __restrict__ cursor,
                               int* __restrict__ esrc, int E) {
  int e = blockIdx.x * blockDim.x + threadIdx.x;
  if (e >= E) return;
  int d = dst[e];
  int p = atomicAdd(&cursor[d], 1);
  esrc[rowstart[d] + p] = src[e];
}

// per-graph node ranges (node2graph is sorted)
__global__ void graph_bounds_kernel(const int* __restrict__ n2g, int* __restrict__ gstart,
                                    int n, int ngraph) {
  int i = blockIdx.x * blockDim.x + threadIdx.x;
  if (i >= n) return;
  int g1 = n2g[i];
  int g0 = (i == 0) ? -1 : n2g[i - 1];
  for (int g = g0 + 1; g <= g1; ++g) gstart[g] = i;
  if (i == n - 1) {
    for (int g = g1 + 1; g <= ngraph; ++g) gstart[g] = n;
  }
}

// ---------------- casts ----------------
__global__ void cast_bf16_kernel(const float* __restrict__ src, unsigned short* __restrict__ dst,
                                 int n4) {
  int i = blockIdx.x * blockDim.x + threadIdx.x;
  if (i >= n4) return;
  float4 v = *(const float4*)(src + (size_t)i * 4);
  ushort4 o;
  o.x = f2bf(v.x); o.y = f2bf(v.y); o.z = f2bf(v.z); o.w = f2bf(v.w);
  *(ushort4*)(dst + (size_t)i * 4) = o;
}

// W[K][256] fp32 -> Wt[256][K] bf16 (n-major, k contiguous)
template<int K>
__global__ void castT_kernel(const float* __restrict__ W, unsigned short* __restrict__ Wt) {
  int tid = blockIdx.x * blockDim.x + threadIdx.x;
  if (tid >= 256 * K) return;
  int n = tid / K, k = tid % K;
  Wt[(size_t)n * K + k] = f2bf(W[(size_t)k * 256 + n]);
}

// ---------------- MFMA GEMM + fused attention logits ----------------
// fs[node][256](bf16) = A[node][K](bf16) @ Wt^T ; el/er[node][8](f32) fused.
// Operand-SWAPPED mfma: acc holds C^T tile, so lane (q,m) owns node row0+m,
// channels ch(nt,i) = nt*16 + q*4 + i  -> ushort4 stores, per-lane el/er dots.
template<int K>
__global__ void gemm_mfma(const unsigned short* __restrict__ A,
                          const unsigned short* __restrict__ Wt,
                          unsigned short* __restrict__ fs,
                          const float* __restrict__ al, const float* __restrict__ ar,
                          float* __restrict__ el, float* __restrict__ er) {
  int lane = threadIdx.x & 63;
  int wave = threadIdx.x >> 6;
  int row0 = blockIdx.x * 64 + wave * 16;
  int m = lane & 15;
  int q = lane >> 4;           // 0..3
  const unsigned short* arow = A + (size_t)(row0 + m) * K + q * 8;
  f32x4 acc[16];
  #pragma unroll
  for (int nt = 0; nt < 16; ++nt) acc[nt] = (f32x4){0.f, 0.f, 0.f, 0.f};
  for (int kc = 0; kc < K; kc += 32) {
    bf16x8 af = *(const bf16x8*)(arow + kc);
    #pragma unroll
    for (int nt = 0; nt < 16; ++nt) {
      bf16x8 bfv = *(const bf16x8*)(Wt + (size_t)(nt * 16 + m) * K + kc + q * 8);
      // swapped: D = Wt_tile * A_tile^T  ==> C^T fragment
      acc[nt] = __builtin_amdgcn_mfma_f32_16x16x32_bf16(bfv, af, acc[nt], 0, 0, 0);
    }
  }
  int node = row0 + m;
  // fused el/er: per-lane dot over its 4 channels per nt, reduce over q
  float elh[NHEAD], erh[NHEAD];
  #pragma unroll
  for (int h = 0; h < NHEAD; ++h) { elh[h] = 0.f; erh[h] = 0.f; }
  #pragma unroll
  for (int nt = 0; nt < 16; ++nt) {
    int h = nt >> 1;
    int c0 = (nt & 1) * 16 + q * 4;
    float4 a4 = *(const float4*)(al + h * 32 + c0);
    float4 r4 = *(const float4*)(ar + h * 32 + c0);
    elh[h] += acc[nt][0] * a4.x + acc[nt][1] * a4.y + acc[nt][2] * a4.z + acc[nt][3] * a4.w;
    erh[h] += acc[nt][0] * r4.x + acc[nt][1] * r4.y + acc[nt][2] * r4.z + acc[nt][3] * r4.w;
  }
  #pragma unroll
  for (int h = 0; h < NHEAD; ++h) {
    elh[h] += __shfl_xor(elh[h], 16); elh[h] += __shfl_xor(elh[h], 32);
    erh[h] += __shfl_xor(erh[h], 16); erh[h] += __shfl_xor(erh[h], 32);
  }
  // stores (buffers padded to MPAD rows; pad rows hold garbage, never read)
  #pragma unroll
  for (int nt = 0; nt < 16; ++nt) {
    ushort4 o;
    o.x = f2bf(acc[nt][0]); o.y = f2bf(acc[nt][1]);
    o.z = f2bf(acc[nt][2]); o.w = f2bf(acc[nt][3]);
    *(ushort4*)(fs + (size_t)node * 256 + nt * 16 + q * 4) = o;
  }
  float2 e2 = make_float2(elh[2 * q], elh[2 * q + 1]);
  float2 r2 = make_float2(erh[2 * q], erh[2 * q + 1]);
  *(float2*)(el + (size_t)node * NHEAD + 2 * q) = e2;
  *(float2*)(er + (size_t)node * NHEAD + 2 * q) = r2;
}

// ---------------- fused edge softmax + aggregation: one wave per dst node ----------------
// 64 edge ids pulled in one coalesced load, __shfl-broadcast, 4-wide load groups.
template<bool RELU, bool BF16OUT>
__global__ void edge_agg_kernel(const int* __restrict__ rowstart, const int* __restrict__ esrc,
                                const float* __restrict__ el, const float* __restrict__ er,
                                const unsigned short* __restrict__ fs,
                                const float* __restrict__ bias,
                                void* __restrict__ out, int nnodes) {
  int gid = blockIdx.x * blockDim.x + threadIdx.x;
  int v = gid >> 6;
  int lane = threadIdx.x & 63;
  if (v >= nnodes) return;
  int h = lane >> 3;
  int row0 = rowstart[v];
  int deg = rowstart[v + 1] - row0;
  float er_vh = er[v * NHEAD + h];
  float4 acc = make_float4(0.f, 0.f, 0.f, 0.f);
  float wsum = 0.f;
  for (int base = 0; base < deg; base += 64) {
    int mrem = deg - base;
    int mm = (mrem < 64) ? mrem : 64;
    int li = (lane < mm) ? lane : (mm - 1);
    int es = esrc[row0 + base + li];   // one coalesced load per 64 edges
    for (int j0 = 0; j0 < mm; j0 += 4) {
      int s0 = __shfl(es, j0);
      int s1 = __shfl(es, j0 + 1);
      int s2 = __shfl(es, j0 + 2);
      int s3 = __shfl(es, j0 + 3);
      float e0 = el[s0 * NHEAD + h];
      float e1 = el[s1 * NHEAD + h];
      float e2 = el[s2 * NHEAD + h];
      float e3 = el[s3 * NHEAD + h];
      ushort4 f0 = *(const ushort4*)&fs[(size_t)s0 * FDIM + lane * 4];
      ushort4 f1 = *(const ushort4*)&fs[(size_t)s1 * FDIM + lane * 4];
      ushort4 f2 = *(const ushort4*)&fs[(size_t)s2 * FDIM + lane * 4];
      ushort4 f3 = *(const ushort4*)&fs[(size_t)s3 * FDIM + lane * 4];
      #define AGG_STEP(t, ev, fv)                                        \
      {                                                                  \
        float x = (ev) + er_vh;                                          \
        x = (x >= 0.f) ? x : SLOPE * x;                                  \
        float w = __expf(x);                                             \
        if (j0 + (t) >= mm) w = 0.f;                                     \
        wsum += w;                                                       \
        acc.x = fmaf(w, b2f((fv).x), acc.x);                             \
        acc.y = fmaf(w, b2f((fv).y), acc.y);                             \
        acc.z = fmaf(w, b2f((fv).z), acc.z);                             \
        acc.w = fmaf(w, b2f((fv).w), acc.w);                             \
      }
      AGG_STEP(0, e0, f0)
      AGG_STEP(1, e1, f1)
      AGG_STEP(2, e2, f2)
      AGG_STEP(3, e3, f3)
      #undef AGG_STEP
    }
  }
  float rdenom = (deg > 0) ? (1.0f / wsum) : 0.f;
  const float4 b = *(const float4*)(bias + lane * 4);
  acc.x = fmaf(acc.x, rdenom, b.x);
  acc.y = fmaf(acc.y, rdenom, b.y);
  acc.z = fmaf(acc.z, rdenom, b.z);
  acc.w = fmaf(acc.w, rdenom, b.w);
  if (RELU) {
    acc.x = fmaxf(acc.x, 0.f); acc.y = fmaxf(acc.y, 0.f);
    acc.z = fmaxf(acc.z, 0.f); acc.w = fmaxf(acc.w, 0.f);
  }
  if (BF16OUT) {
    ushort4 o;
    o.x = f2bf(acc.x); o.y = f2bf(acc.y); o.z = f2bf(acc.z); o.w = f2bf(acc.w);
    *(ushort4*)((unsigned short*)out + (size_t)v * FDIM + lane * 4) = o;
  } else {
    *(float4*)((float*)out + (size_t)v * FDIM + lane * 4) = acc;
  }
}

// ---------------- per-graph sum pool (node-parallel, register-accumulated) ----------------
__global__ void pool_sum_kernel(const float* __restrict__ h2, const int* __restrict__ n2g,
                                float* __restrict__ hg, int nnodes) {
  int wave = (blockIdx.x * blockDim.x + threadIdx.x) >> 6;
  int lane = threadIdx.x & 63;
  int n0 = wave * 64;
  if (n0 >= nnodes) return;
  int n1 = min(n0 + 64, nnodes);
  int curg = n2g[n0];
  float4 acc = make_float4(0.f, 0.f, 0.f, 0.f);
  for (int n = n0; n < n1; ++n) {
    int g = n2g[n];
    if (g != curg) {
      float* p = &hg[(size_t)curg * FDIM + lane * 4];
      atomicAdd(p + 0, acc.x); atomicAdd(p + 1, acc.y);
      atomicAdd(p + 2, acc.z); atomicAdd(p + 3, acc.w);
      acc = make_float4(0.f, 0.f, 0.f, 0.f);
      curg = g;
    }
    float4 v = *(const float4*)&h2[(size_t)n * FDIM + lane * 4];
    acc.x += v.x; acc.y += v.y; acc.z += v.z; acc.w += v.w;
  }
  float* p = &hg[(size_t)curg * FDIM + lane * 4];
  atomicAdd(p + 0, acc.x); atomicAdd(p + 1, acc.y);
  atomicAdd(p + 2, acc.z); atomicAdd(p + 3, acc.w);
}

// ---------------- classifier (divides pooled sums by per-graph count) ----------------
__global__ void classifier_kernel(const float* __restrict__ hgsum, const int* __restrict__ gstart,
                                  const float* __restrict__ Wc, const float* __restrict__ bcv,
                                  float* __restrict__ out) {
  int tid = blockIdx.x * blockDim.x + threadIdx.x;
  if (tid >= N_GRAPHS * NC) return;
  int b = tid / NC, j = tid % NC;
  int cnt = gstart[b + 1] - gstart[b];
  float inv = (cnt > 0) ? (1.0f / (float)cnt) : 1.0f;
  float s = 0.f;
  for (int c = 0; c < FDIM; ++c) s += hgsum[b * FDIM + c] * Wc[c * NC + j];
  out[tid] = s * inv + bcv[j];
}

extern "C" void kernel_launch(void* const* d_in, const int* in_sizes, int n_in,
                              void* d_out, int out_size, void* d_ws, size_t ws_size,
                              hipStream_t stream) {
  const float* feat = (const float*)d_in[0];
  const int* src    = (const int*)d_in[1];
  const int* dst    = (const int*)d_in[2];
  const int* n2g    = (const int*)d_in[3];
  const float* W1  = (const float*)d_in[4];
  const float* al1 = (const float*)d_in[5];
  const float* ar1 = (const float*)d_in[6];
  const float* b1  = (const float*)d_in[7];
  const float* W2  = (const float*)d_in[8];
  const float* al2 = (const float*)d_in[9];
  const float* ar2 = (const float*)d_in[10];
  const float* b2  = (const float*)d_in[11];
  const float* Wc  = (const float*)d_in[12];
  const float* bc  = (const float*)d_in[13];
  float* out = (float*)d_out;

  char* wp = (char*)d_ws;
  auto carve = [&](size_t bytes) -> void* {
    void* p = (void*)wp;
    wp += (bytes + 255) & ~(size_t)255;
    return p;
  };
  unsigned short* fs = (unsigned short*)carve((size_t)MPAD * FDIM * 2);  // 25.6 MB bf16 (padded)
  // region R1 (51.2 MB): A1_bf + h1_bf live first, then h2(f32) overwrites both
  char* R1  = (char*)carve((size_t)N_NODES * FDIM * 4);
  unsigned short* A1 = (unsigned short*)R1;                            // [MPAD][128] bf16
  unsigned short* h1 = (unsigned short*)(R1 + (size_t)MPAD * 128 * 2); // [MPAD][256] bf16
  float* h2 = (float*)R1;                                              // [N][256] f32 after h1 dead
  unsigned short* Wt1 = (unsigned short*)carve((size_t)256 * 128 * 2);
  unsigned short* Wt2 = (unsigned short*)carve((size_t)256 * 256 * 2);
  float* el      = (float*)carve((size_t)MPAD * NHEAD * 4);
  float* er      = (float*)carve((size_t)MPAD * NHEAD * 4);
  int* rowstart  = (int*)  carve((size_t)(N_NODES + 1) * 4);
  int* cursor    = (int*)  carve((size_t)N_NODES * 4);
  int* esrc      = (int*)  carve((size_t)N_EDGES * 4);
  int* gstart    = (int*)  carve((size_t)(N_GRAPHS + 1) * 4);
  float* hg      = (float*)carve((size_t)N_GRAPHS * FDIM * 4);
  (void)ws_size; (void)n_in; (void)in_sizes; (void)out_size;

  // CSR build + weight prep
  hipMemsetAsync(cursor, 0, (size_t)N_NODES * 4, stream);
  hipMemsetAsync(hg, 0, (size_t)N_GRAPHS * FDIM * 4, stream);
  hist_kernel<<<(N_EDGES + 255) / 256, 256, 0, stream>>>(dst, cursor, N_EDGES);
  scan_kernel<<<1, 1024, 0, stream>>>(cursor, rowstart, N_NODES);
  hipMemsetAsync(cursor, 0, (size_t)N_NODES * 4, stream);
  scatter_kernel<<<(N_EDGES + 255) / 256, 256, 0, stream>>>(src, dst, rowstart, cursor, esrc, N_EDGES);
  graph_bounds_kernel<<<(N_NODES + 255) / 256, 256, 0, stream>>>(n2g, gstart, N_NODES, N_GRAPHS);
  castT_kernel<128><<<(256 * 128 + 255) / 256, 256, 0, stream>>>(W1, Wt1);
  castT_kernel<256><<<(256 * 256 + 255) / 256, 256, 0, stream>>>(W2, Wt2);
  cast_bf16_kernel<<<(N_NODES * 128 / 4 + 255) / 256, 256, 0, stream>>>(feat, A1, N_NODES * 128 / 4);

  // layer 1 (gemm writes fs + el + er)
  gemm_mfma<128><<<MPAD / 64, 256, 0, stream>>>(A1, Wt1, fs, al1, ar1, el, er);
  edge_agg_kernel<true, true><<<(N_NODES * 64 + 255) / 256, 256, 0, stream>>>(
      rowstart, esrc, el, er, fs, b1, (void*)h1, N_NODES);

  // layer 2
  gemm_mfma<256><<<MPAD / 64, 256, 0, stream>>>(h1, Wt2, fs, al2, ar2, el, er);
  edge_agg_kernel<false, false><<<(N_NODES * 64 + 255) / 256, 256, 0, stream>>>(
      rowstart, esrc, el, er, fs, b2, (void*)h2, N_NODES);

  // readout
  pool_sum_kernel<<<((N_NODES + 63) / 64 * 64 + 255) / 256, 256, 0, stream>>>(h2, n2g, hg, N_NODES);
  classifier_kernel<<<(N_GRAPHS * NC + 255) / 256, 256, 0, stream>>>(hg, gstart, Wc, bc, out);
}

// Round 7
// 432.597 us; speedup vs baseline: 1.8169x; 1.0537x over previous
//
#include <hip/hip_runtime.h>
#include <hip/hip_bf16.h>

#define N_NODES 50000
#define N_EDGES 500000
#define N_GRAPHS 64
#define FDIM 256   // H*HID
#define NHEAD 8
#define NC 10
#define SLOPE 0.2f
#define MPAD 50048  // N_NODES rounded up to 64

typedef __attribute__((ext_vector_type(8))) short bf16x8;
typedef __attribute__((ext_vector_type(4))) float f32x4;

__device__ __forceinline__ unsigned short f2bf(float f) {
  unsigned x = __float_as_uint(f);
  x += 0x7fff + ((x >> 16) & 1);   // RNE
  return (unsigned short)(x >> 16);
}
__device__ __forceinline__ float b2f(unsigned short u) {
  return __uint_as_float((unsigned)u << 16);
}

// ---------------- CSR build ----------------
__global__ void hist_kernel(const int* __restrict__ dst, int* __restrict__ deg, int E) {
  int e = blockIdx.x * blockDim.x + threadIdx.x;
  if (e < E) atomicAdd(&deg[dst[e]], 1);
}

// single-block exclusive scan of deg[0..n) -> rowstart[0..n]
__global__ void scan_kernel(const int* __restrict__ deg, int* __restrict__ rowstart, int n) {
  __shared__ int wsum[16];
  __shared__ int carry_s;
  int t = threadIdx.x, lane = t & 63, w = t >> 6;
  if (t == 0) carry_s = 0;
  __syncthreads();
  for (int base = 0; base < n; base += 1024) {
    int i = base + t;
    int v = (i < n) ? deg[i] : 0;
    int x = v;
    #pragma unroll
    for (int off = 1; off < 64; off <<= 1) {
      int y = __shfl_up(x, off);
      if (lane >= off) x += y;
    }
    if (lane == 63) wsum[w] = x;
    __syncthreads();
    if (w == 0 && lane < 16) {
      int s = wsum[lane];
      #pragma unroll
      for (int off = 1; off < 16; off <<= 1) {
        int y = __shfl_up(s, off);
        if (lane >= off) s += y;
      }
      wsum[lane] = s;  // inclusive over wave sums
    }
    __syncthreads();
    int woff = (w > 0) ? wsum[w - 1] : 0;
    int incl = x + woff;
    int carry = carry_s;
    if (i < n) rowstart[i] = carry + incl - v;
    __syncthreads();
    if (t == 1023) carry_s = carry + incl;
    __syncthreads();
  }
  if (t == 0) rowstart[n] = carry_s;
}

__global__ void scatter_kernel(const int* __restrict__ src, const int* __restrict__ dst,
                               const int* __restrict__ rowstart, int* __restrict__ cursor,
                               int* __restrict__ esrc, int E) {
  int e = blockIdx.x * blockDim.x + threadIdx.x;
  if (e >= E) return;
  int d = dst[e];
  int p = atomicAdd(&cursor[d], 1);
  esrc[rowstart[d] + p] = src[e];
}

// per-graph node ranges (node2graph is sorted)
__global__ void graph_bounds_kernel(const int* __restrict__ n2g, int* __restrict__ gstart,
                                    int n, int ngraph) {
  int i = blockIdx.x * blockDim.x + threadIdx.x;
  if (i >= n) return;
  int g1 = n2g[i];
  int g0 = (i == 0) ? -1 : n2g[i - 1];
  for (int g = g0 + 1; g <= g1; ++g) gstart[g] = i;
  if (i == n - 1) {
    for (int g = g1 + 1; g <= ngraph; ++g) gstart[g] = n;
  }
}

// ---------------- casts ----------------
__global__ void cast_bf16_kernel(const float* __restrict__ src, unsigned short* __restrict__ dst,
                                 int n4) {
  int i = blockIdx.x * blockDim.x + threadIdx.x;
  if (i >= n4) return;
  float4 v = *(const float4*)(src + (size_t)i * 4);
  ushort4 o;
  o.x = f2bf(v.x); o.y = f2bf(v.y); o.z = f2bf(v.z); o.w = f2bf(v.w);
  *(ushort4*)(dst + (size_t)i * 4) = o;
}

// W[K][256] fp32 -> Wt[256][K] bf16 (n-major, k contiguous)
template<int K>
__global__ void castT_kernel(const float* __restrict__ W, unsigned short* __restrict__ Wt) {
  int tid = blockIdx.x * blockDim.x + threadIdx.x;
  if (tid >= 256 * K) return;
  int n = tid / K, k = tid % K;
  Wt[(size_t)n * K + k] = f2bf(W[(size_t)k * 256 + n]);
}

// ---------------- MFMA GEMM + fused attention logits ----------------
// fs[node][256](bf16) = A[node][K](bf16) @ Wt^T ; el/er[node][8](f32) fused.
// Block = 4 waves covering ONE 16-row stripe; wave w owns cols w*64..w*64+63
// (nt 0..3 -> global col-tile w*4+nt). Grid = MPAD/16 blocks -> 12512 waves,
// 4x R6's concurrency; A-frags hoisted (all independent loads in flight).
// Operand-swapped mfma => lane (q,m) owns node row0+m, chans ntg*16+q*4+i.
// Wave w's cols hold exactly heads 2w,2w+1 -> el/er reduce stays wave-local.
template<int K>
__global__ void gemm_mfma(const unsigned short* __restrict__ A,
                          const unsigned short* __restrict__ Wt,
                          unsigned short* __restrict__ fs,
                          const float* __restrict__ al, const float* __restrict__ ar,
                          float* __restrict__ el, float* __restrict__ er) {
  constexpr int KC = K / 32;
  int lane = threadIdx.x & 63;
  int w = threadIdx.x >> 6;    // col-group 0..3
  int row0 = blockIdx.x * 16;
  int m = lane & 15;
  int q = lane >> 4;           // 0..3
  int node = row0 + m;
  const unsigned short* arow = A + (size_t)node * K + q * 8;
  // hoist all A fragments (independent loads, deep MLP)
  bf16x8 af[KC];
  #pragma unroll
  for (int kc = 0; kc < KC; ++kc) af[kc] = *(const bf16x8*)(arow + kc * 32);
  f32x4 acc[4];
  #pragma unroll
  for (int nt = 0; nt < 4; ++nt) acc[nt] = (f32x4){0.f, 0.f, 0.f, 0.f};
  const unsigned short* wbase = Wt + (size_t)(w * 64 + m) * K + q * 8;
  #pragma unroll
  for (int kc = 0; kc < KC; ++kc) {
    #pragma unroll
    for (int nt = 0; nt < 4; ++nt) {
      bf16x8 bfv = *(const bf16x8*)(wbase + (size_t)nt * 16 * K + kc * 32);
      acc[nt] = __builtin_amdgcn_mfma_f32_16x16x32_bf16(bfv, af[kc], acc[nt], 0, 0, 0);
    }
  }
  // fused el/er for this wave's two heads (2w, 2w+1)
  float elh[2] = {0.f, 0.f}, erh[2] = {0.f, 0.f};
  #pragma unroll
  for (int nt = 0; nt < 4; ++nt) {
    int ntg = w * 4 + nt;
    int h = ntg >> 1;
    int c0 = (ntg & 1) * 16 + q * 4;
    float4 a4 = *(const float4*)(al + h * 32 + c0);
    float4 r4 = *(const float4*)(ar + h * 32 + c0);
    elh[nt >> 1] += acc[nt][0] * a4.x + acc[nt][1] * a4.y + acc[nt][2] * a4.z + acc[nt][3] * a4.w;
    erh[nt >> 1] += acc[nt][0] * r4.x + acc[nt][1] * r4.y + acc[nt][2] * r4.z + acc[nt][3] * r4.w;
  }
  #pragma unroll
  for (int i = 0; i < 2; ++i) {
    elh[i] += __shfl_xor(elh[i], 16); elh[i] += __shfl_xor(elh[i], 32);
    erh[i] += __shfl_xor(erh[i], 16); erh[i] += __shfl_xor(erh[i], 32);
  }
  // stores (buffers padded to MPAD rows; pad rows hold garbage, never read)
  #pragma unroll
  for (int nt = 0; nt < 4; ++nt) {
    ushort4 o;
    o.x = f2bf(acc[nt][0]); o.y = f2bf(acc[nt][1]);
    o.z = f2bf(acc[nt][2]); o.w = f2bf(acc[nt][3]);
    *(ushort4*)(fs + (size_t)node * 256 + w * 64 + nt * 16 + q * 4) = o;
  }
  if (q == 0) {
    *(float2*)(el + (size_t)node * NHEAD + 2 * w) = make_float2(elh[0], elh[1]);
    *(float2*)(er + (size_t)node * NHEAD + 2 * w) = make_float2(erh[0], erh[1]);
  }
}

// ---------------- fused edge softmax + aggregation: one wave per dst node ----------------
// 64 edge ids pulled in one coalesced load, __shfl-broadcast, 4-wide load groups.
template<bool RELU, bool BF16OUT>
__global__ void edge_agg_kernel(const int* __restrict__ rowstart, const int* __restrict__ esrc,
                                const float* __restrict__ el, const float* __restrict__ er,
                                const unsigned short* __restrict__ fs,
                                const float* __restrict__ bias,
                                void* __restrict__ out, int nnodes) {
  int gid = blockIdx.x * blockDim.x + threadIdx.x;
  int v = gid >> 6;
  int lane = threadIdx.x & 63;
  if (v >= nnodes) return;
  int h = lane >> 3;
  int row0 = rowstart[v];
  int deg = rowstart[v + 1] - row0;
  float er_vh = er[v * NHEAD + h];
  float4 acc = make_float4(0.f, 0.f, 0.f, 0.f);
  float wsum = 0.f;
  for (int base = 0; base < deg; base += 64) {
    int mrem = deg - base;
    int mm = (mrem < 64) ? mrem : 64;
    int li = (lane < mm) ? lane : (mm - 1);
    int es = esrc[row0 + base + li];   // one coalesced load per 64 edges
    for (int j0 = 0; j0 < mm; j0 += 4) {
      int s0 = __shfl(es, j0);
      int s1 = __shfl(es, j0 + 1);
      int s2 = __shfl(es, j0 + 2);
      int s3 = __shfl(es, j0 + 3);
      float e0 = el[s0 * NHEAD + h];
      float e1 = el[s1 * NHEAD + h];
      float e2 = el[s2 * NHEAD + h];
      float e3 = el[s3 * NHEAD + h];
      ushort4 f0 = *(const ushort4*)&fs[(size_t)s0 * FDIM + lane * 4];
      ushort4 f1 = *(const ushort4*)&fs[(size_t)s1 * FDIM + lane * 4];
      ushort4 f2 = *(const ushort4*)&fs[(size_t)s2 * FDIM + lane * 4];
      ushort4 f3 = *(const ushort4*)&fs[(size_t)s3 * FDIM + lane * 4];
      #define AGG_STEP(t, ev, fv)                                        \
      {                                                                  \
        float x = (ev) + er_vh;                                          \
        x = (x >= 0.f) ? x : SLOPE * x;                                  \
        float w = __expf(x);                                             \
        if (j0 + (t) >= mm) w = 0.f;                                     \
        wsum += w;                                                       \
        acc.x = fmaf(w, b2f((fv).x), acc.x);                             \
        acc.y = fmaf(w, b2f((fv).y), acc.y);                             \
        acc.z = fmaf(w, b2f((fv).z), acc.z);                             \
        acc.w = fmaf(w, b2f((fv).w), acc.w);                             \
      }
      AGG_STEP(0, e0, f0)
      AGG_STEP(1, e1, f1)
      AGG_STEP(2, e2, f2)
      AGG_STEP(3, e3, f3)
      #undef AGG_STEP
    }
  }
  float rdenom = (deg > 0) ? (1.0f / wsum) : 0.f;
  const float4 b = *(const float4*)(bias + lane * 4);
  acc.x = fmaf(acc.x, rdenom, b.x);
  acc.y = fmaf(acc.y, rdenom, b.y);
  acc.z = fmaf(acc.z, rdenom, b.z);
  acc.w = fmaf(acc.w, rdenom, b.w);
  if (RELU) {
    acc.x = fmaxf(acc.x, 0.f); acc.y = fmaxf(acc.y, 0.f);
    acc.z = fmaxf(acc.z, 0.f); acc.w = fmaxf(acc.w, 0.f);
  }
  if (BF16OUT) {
    ushort4 o;
    o.x = f2bf(acc.x); o.y = f2bf(acc.y); o.z = f2bf(acc.z); o.w = f2bf(acc.w);
    *(ushort4*)((unsigned short*)out + (size_t)v * FDIM + lane * 4) = o;
  } else {
    *(float4*)((float*)out + (size_t)v * FDIM + lane * 4) = acc;
  }
}

// ---------------- per-graph sum pool (node-parallel, register-accumulated) ----------------
__global__ void pool_sum_kernel(const float* __restrict__ h2, const int* __restrict__ n2g,
                                float* __restrict__ hg, int nnodes) {
  int wave = (blockIdx.x * blockDim.x + threadIdx.x) >> 6;
  int lane = threadIdx.x & 63;
  int n0 = wave * 64;
  if (n0 >= nnodes) return;
  int n1 = min(n0 + 64, nnodes);
  int curg = n2g[n0];
  float4 acc = make_float4(0.f, 0.f, 0.f, 0.f);
  for (int n = n0; n < n1; ++n) {
    int g = n2g[n];
    if (g != curg) {
      float* p = &hg[(size_t)curg * FDIM + lane * 4];
      atomicAdd(p + 0, acc.x); atomicAdd(p + 1, acc.y);
      atomicAdd(p + 2, acc.z); atomicAdd(p + 3, acc.w);
      acc = make_float4(0.f, 0.f, 0.f, 0.f);
      curg = g;
    }
    float4 v = *(const float4*)&h2[(size_t)n * FDIM + lane * 4];
    acc.x += v.x; acc.y += v.y; acc.z += v.z; acc.w += v.w;
  }
  float* p = &hg[(size_t)curg * FDIM + lane * 4];
  atomicAdd(p + 0, acc.x); atomicAdd(p + 1, acc.y);
  atomicAdd(p + 2, acc.z); atomicAdd(p + 3, acc.w);
}

// ---------------- classifier (divides pooled sums by per-graph count) ----------------
__global__ void classifier_kernel(const float* __restrict__ hgsum, const int* __restrict__ gstart,
                                  const float* __restrict__ Wc, const float* __restrict__ bcv,
                                  float* __restrict__ out) {
  int tid = blockIdx.x * blockDim.x + threadIdx.x;
  if (tid >= N_GRAPHS * NC) return;
  int b = tid / NC, j = tid % NC;
  int cnt = gstart[b + 1] - gstart[b];
  float inv = (cnt > 0) ? (1.0f / (float)cnt) : 1.0f;
  float s = 0.f;
  for (int c = 0; c < FDIM; ++c) s += hgsum[b * FDIM + c] * Wc[c * NC + j];
  out[tid] = s * inv + bcv[j];
}

extern "C" void kernel_launch(void* const* d_in, const int* in_sizes, int n_in,
                              void* d_out, int out_size, void* d_ws, size_t ws_size,
                              hipStream_t stream) {
  const float* feat = (const float*)d_in[0];
  const int* src    = (const int*)d_in[1];
  const int* dst    = (const int*)d_in[2];
  const int* n2g    = (const int*)d_in[3];
  const float* W1  = (const float*)d_in[4];
  const float* al1 = (const float*)d_in[5];
  const float* ar1 = (const float*)d_in[6];
  const float* b1  = (const float*)d_in[7];
  const float* W2  = (const float*)d_in[8];
  const float* al2 = (const float*)d_in[9];
  const float* ar2 = (const float*)d_in[10];
  const float* b2  = (const float*)d_in[11];
  const float* Wc  = (const float*)d_in[12];
  const float* bc  = (const float*)d_in[13];
  float* out = (float*)d_out;

  char* wp = (char*)d_ws;
  auto carve = [&](size_t bytes) -> void* {
    void* p = (void*)wp;
    wp += (bytes + 255) & ~(size_t)255;
    return p;
  };
  unsigned short* fs = (unsigned short*)carve((size_t)MPAD * FDIM * 2);  // 25.6 MB bf16 (padded)
  // region R1 (51.2 MB): A1_bf + h1_bf live first, then h2(f32) overwrites both
  char* R1  = (char*)carve((size_t)N_NODES * FDIM * 4);
  unsigned short* A1 = (unsigned short*)R1;                            // [MPAD][128] bf16
  unsigned short* h1 = (unsigned short*)(R1 + (size_t)MPAD * 128 * 2); // [MPAD][256] bf16
  float* h2 = (float*)R1;                                              // [N][256] f32 after h1 dead
  unsigned short* Wt1 = (unsigned short*)carve((size_t)256 * 128 * 2);
  unsigned short* Wt2 = (unsigned short*)carve((size_t)256 * 256 * 2);
  float* el      = (float*)carve((size_t)MPAD * NHEAD * 4);
  float* er      = (float*)carve((size_t)MPAD * NHEAD * 4);
  int* rowstart  = (int*)  carve((size_t)(N_NODES + 1) * 4);
  int* cursor    = (int*)  carve((size_t)N_NODES * 4);
  int* esrc      = (int*)  carve((size_t)N_EDGES * 4);
  int* gstart    = (int*)  carve((size_t)(N_GRAPHS + 1) * 4);
  float* hg      = (float*)carve((size_t)N_GRAPHS * FDIM * 4);
  (void)ws_size; (void)n_in; (void)in_sizes; (void)out_size;

  // CSR build + weight prep
  hipMemsetAsync(cursor, 0, (size_t)N_NODES * 4, stream);
  hipMemsetAsync(hg, 0, (size_t)N_GRAPHS * FDIM * 4, stream);
  hist_kernel<<<(N_EDGES + 255) / 256, 256, 0, stream>>>(dst, cursor, N_EDGES);
  scan_kernel<<<1, 1024, 0, stream>>>(cursor, rowstart, N_NODES);
  hipMemsetAsync(cursor, 0, (size_t)N_NODES * 4, stream);
  scatter_kernel<<<(N_EDGES + 255) / 256, 256, 0, stream>>>(src, dst, rowstart, cursor, esrc, N_EDGES);
  graph_bounds_kernel<<<(N_NODES + 255) / 256, 256, 0, stream>>>(n2g, gstart, N_NODES, N_GRAPHS);
  castT_kernel<128><<<(256 * 128 + 255) / 256, 256, 0, stream>>>(W1, Wt1);
  castT_kernel<256><<<(256 * 256 + 255) / 256, 256, 0, stream>>>(W2, Wt2);
  cast_bf16_kernel<<<(N_NODES * 128 / 4 + 255) / 256, 256, 0, stream>>>(feat, A1, N_NODES * 128 / 4);

  // layer 1 (gemm writes fs + el + er)
  gemm_mfma<128><<<MPAD / 16, 256, 0, stream>>>(A1, Wt1, fs, al1, ar1, el, er);
  edge_agg_kernel<true, true><<<(N_NODES * 64 + 255) / 256, 256, 0, stream>>>(
      rowstart, esrc, el, er, fs, b1, (void*)h1, N_NODES);

  // layer 2
  gemm_mfma<256><<<MPAD / 16, 256, 0, stream>>>(h1, Wt2, fs, al2, ar2, el, er);
  edge_agg_kernel<false, false><<<(N_NODES * 64 + 255) / 256, 256, 0, stream>>>(
      rowstart, esrc, el, er, fs, b2, (void*)h2, N_NODES);

  // readout
  pool_sum_kernel<<<((N_NODES + 63) / 64 * 64 + 255) / 256, 256, 0, stream>>>(h2, n2g, hg, N_NODES);
  classifier_kernel<<<(N_GRAPHS * NC + 255) / 256, 256, 0, stream>>>(hg, gstart, Wc, bc, out);
}

// Round 8
// 372.946 us; speedup vs baseline: 2.1075x; 1.1599x over previous
//
#include <hip/hip_runtime.h>
#include <hip/hip_bf16.h>

#define N_NODES 50000
#define N_EDGES 500000
#define N_GRAPHS 64
#define FDIM 256   // H*HID
#define NHEAD 8
#define NC 10
#define SLOPE 0.2f
#define MPAD 50048  // N_NODES rounded up to 64

typedef __attribute__((ext_vector_type(8))) short bf16x8;
typedef __attribute__((ext_vector_type(4))) float f32x4;

__device__ __forceinline__ unsigned short f2bf(float f) {
  unsigned x = __float_as_uint(f);
  x += 0x7fff + ((x >> 16) & 1);   // RNE
  return (unsigned short)(x >> 16);
}
__device__ __forceinline__ float b2f(unsigned short u) {
  return __uint_as_float((unsigned)u << 16);
}

// ---------------- CSR build ----------------
__global__ void hist_kernel(const int* __restrict__ dst, int* __restrict__ deg, int E) {
  int e = blockIdx.x * blockDim.x + threadIdx.x;
  if (e < E) atomicAdd(&deg[dst[e]], 1);
}

// single-block exclusive scan of deg[0..n) -> rowstart[0..n]
__global__ void scan_kernel(const int* __restrict__ deg, int* __restrict__ rowstart, int n) {
  __shared__ int wsum[16];
  __shared__ int carry_s;
  int t = threadIdx.x, lane = t & 63, w = t >> 6;
  if (t == 0) carry_s = 0;
  __syncthreads();
  for (int base = 0; base < n; base += 1024) {
    int i = base + t;
    int v = (i < n) ? deg[i] : 0;
    int x = v;
    #pragma unroll
    for (int off = 1; off < 64; off <<= 1) {
      int y = __shfl_up(x, off);
      if (lane >= off) x += y;
    }
    if (lane == 63) wsum[w] = x;
    __syncthreads();
    if (w == 0 && lane < 16) {
      int s = wsum[lane];
      #pragma unroll
      for (int off = 1; off < 16; off <<= 1) {
        int y = __shfl_up(s, off);
        if (lane >= off) s += y;
      }
      wsum[lane] = s;  // inclusive over wave sums
    }
    __syncthreads();
    int woff = (w > 0) ? wsum[w - 1] : 0;
    int incl = x + woff;
    int carry = carry_s;
    if (i < n) rowstart[i] = carry + incl - v;
    __syncthreads();
    if (t == 1023) carry_s = carry + incl;
    __syncthreads();
  }
  if (t == 0) rowstart[n] = carry_s;
}

__global__ void scatter_kernel(const int* __restrict__ src, const int* __restrict__ dst,
                               const int* __restrict__ rowstart, int* __restrict__ cursor,
                               int* __restrict__ esrc, int E) {
  int e = blockIdx.x * blockDim.x + threadIdx.x;
  if (e >= E) return;
  int d = dst[e];
  int p = atomicAdd(&cursor[d], 1);
  esrc[rowstart[d] + p] = src[e];
}

// per-graph node ranges (node2graph is sorted)
__global__ void graph_bounds_kernel(const int* __restrict__ n2g, int* __restrict__ gstart,
                                    int n, int ngraph) {
  int i = blockIdx.x * blockDim.x + threadIdx.x;
  if (i >= n) return;
  int g1 = n2g[i];
  int g0 = (i == 0) ? -1 : n2g[i - 1];
  for (int g = g0 + 1; g <= g1; ++g) gstart[g] = i;
  if (i == n - 1) {
    for (int g = g1 + 1; g <= ngraph; ++g) gstart[g] = n;
  }
}

// W[K][256] fp32 -> Wt[256][K] bf16 (n-major, k contiguous)
template<int K>
__global__ void castT_kernel(const float* __restrict__ W, unsigned short* __restrict__ Wt) {
  int tid = blockIdx.x * blockDim.x + threadIdx.x;
  if (tid >= 256 * K) return;
  int n = tid / K, k = tid % K;
  Wt[(size_t)n * K + k] = f2bf(W[(size_t)k * 256 + n]);
}

// ---------------- LDS-staged MFMA GEMM + fused attention logits ----------------
// fs[node][256](bf16) = A[node][K] @ Wt^T ; el/er[node][8](f32) fused.
// Block 256 thr, tile 64 rows x 256 cols, BK=32. Coalesced global->reg staging
// (overlapped with compute), ds_write to single 20KB LDS buffer, ds_read_b128
// fragments. AF32: A is fp32 (feat), converted to bf16 during staging.
// Operand-swapped mfma => lane (q,m) of wave w owns node blk*64+w*16+m,
// channels nt*16+q*4+i; all 8 heads' el/er reduced wave-locally.
template<int K, bool AF32>
__global__ void gemm_mfma(const void* __restrict__ Avoid,
                          const unsigned short* __restrict__ Wt,
                          unsigned short* __restrict__ fs,
                          const float* __restrict__ al, const float* __restrict__ ar,
                          float* __restrict__ el, float* __restrict__ er, int nrows) {
  constexpr int KC = K / 32;
  __shared__ __align__(16) unsigned short Albs[64 * 32];    // [row][32k] 4 KB
  __shared__ __align__(16) unsigned short Wlds[256 * 32];   // [n][32k] 16 KB
  const float* Af = (const float*)Avoid;
  const unsigned short* Ab = (const unsigned short*)Avoid;
  int t = threadIdx.x;
  int lane = t & 63;
  int w = t >> 6;
  int row0 = blockIdx.x * 64;
  int m = lane & 15;
  int q = lane >> 4;
  // staging registers
  float4 a32[2];
  bf16x8 a16;
  bf16x8 wtr[4];
  int arow = t >> 2, apiece = t & 3;                 // bf16 A staging coords
  int agrow = min(row0 + arow, nrows - 1);
  int frow0 = t >> 3, fquad0 = t & 7;                // f32 A staging coords (j=0)
  int frow1 = (256 + t) >> 3, fquad1 = t & 7;        // j=1
  int fgrow0 = min(row0 + frow0, nrows - 1);
  int fgrow1 = min(row0 + frow1, nrows - 1);

  auto stage = [&](int kc) {
    if (AF32) {
      a32[0] = *(const float4*)(Af + (size_t)fgrow0 * K + kc * 32 + fquad0 * 4);
      a32[1] = *(const float4*)(Af + (size_t)fgrow1 * K + kc * 32 + fquad1 * 4);
    } else {
      a16 = *(const bf16x8*)(Ab + (size_t)agrow * K + kc * 32 + apiece * 8);
    }
    #pragma unroll
    for (int j = 0; j < 4; ++j) {
      int row = j * 64 + (t >> 2);
      wtr[j] = *(const bf16x8*)(Wt + (size_t)row * K + kc * 32 + (t & 3) * 8);
    }
  };
  auto commit = [&]() {
    if (AF32) {
      ushort4 o0, o1;
      o0.x = f2bf(a32[0].x); o0.y = f2bf(a32[0].y); o0.z = f2bf(a32[0].z); o0.w = f2bf(a32[0].w);
      o1.x = f2bf(a32[1].x); o1.y = f2bf(a32[1].y); o1.z = f2bf(a32[1].z); o1.w = f2bf(a32[1].w);
      *(ushort4*)(Albs + frow0 * 32 + fquad0 * 4) = o0;
      *(ushort4*)(Albs + frow1 * 32 + fquad1 * 4) = o1;
    } else {
      *(bf16x8*)(Albs + arow * 32 + apiece * 8) = a16;
    }
    #pragma unroll
    for (int j = 0; j < 4; ++j) {
      int row = j * 64 + (t >> 2);
      *(bf16x8*)(Wlds + row * 32 + (t & 3) * 8) = wtr[j];
    }
  };

  f32x4 acc[16];
  #pragma unroll
  for (int nt = 0; nt < 16; ++nt) acc[nt] = (f32x4){0.f, 0.f, 0.f, 0.f};

  stage(0);
  commit();
  for (int kc = 0; kc < KC; ++kc) {
    __syncthreads();                 // staged chunk visible
    if (kc + 1 < KC) stage(kc + 1);  // overlap next-chunk global loads with compute
    bf16x8 af = *(const bf16x8*)(Albs + (w * 16 + m) * 32 + q * 8);
    #pragma unroll
    for (int nt = 0; nt < 16; ++nt) {
      bf16x8 bfv = *(const bf16x8*)(Wlds + (nt * 16 + m) * 32 + q * 8);
      acc[nt] = __builtin_amdgcn_mfma_f32_16x16x32_bf16(bfv, af, acc[nt], 0, 0, 0);
    }
    __syncthreads();                 // all reads of chunk done
    if (kc + 1 < KC) commit();
  }

  int node = row0 + w * 16 + m;
  // fused el/er over all 8 heads
  float elh[NHEAD], erh[NHEAD];
  #pragma unroll
  for (int h = 0; h < NHEAD; ++h) { elh[h] = 0.f; erh[h] = 0.f; }
  #pragma unroll
  for (int nt = 0; nt < 16; ++nt) {
    int h = nt >> 1;
    int c0 = (nt & 1) * 16 + q * 4;
    float4 a4 = *(const float4*)(al + h * 32 + c0);
    float4 r4 = *(const float4*)(ar + h * 32 + c0);
    elh[h] += acc[nt][0] * a4.x + acc[nt][1] * a4.y + acc[nt][2] * a4.z + acc[nt][3] * a4.w;
    erh[h] += acc[nt][0] * r4.x + acc[nt][1] * r4.y + acc[nt][2] * r4.z + acc[nt][3] * r4.w;
  }
  #pragma unroll
  for (int h = 0; h < NHEAD; ++h) {
    elh[h] += __shfl_xor(elh[h], 16); elh[h] += __shfl_xor(elh[h], 32);
    erh[h] += __shfl_xor(erh[h], 16); erh[h] += __shfl_xor(erh[h], 32);
  }
  // stores (fs/el/er padded to MPAD rows; pad rows garbage, never read)
  #pragma unroll
  for (int nt = 0; nt < 16; ++nt) {
    ushort4 o;
    o.x = f2bf(acc[nt][0]); o.y = f2bf(acc[nt][1]);
    o.z = f2bf(acc[nt][2]); o.w = f2bf(acc[nt][3]);
    *(ushort4*)(fs + (size_t)node * 256 + nt * 16 + q * 4) = o;
  }
  *(float2*)(el + (size_t)node * NHEAD + 2 * q) = make_float2(elh[2 * q], elh[2 * q + 1]);
  *(float2*)(er + (size_t)node * NHEAD + 2 * q) = make_float2(erh[2 * q], erh[2 * q + 1]);
}

// ---------------- fused edge softmax + aggregation: one wave per dst node ----------------
template<bool RELU, bool BF16OUT>
__global__ void edge_agg_kernel(const int* __restrict__ rowstart, const int* __restrict__ esrc,
                                const float* __restrict__ el, const float* __restrict__ er,
                                const unsigned short* __restrict__ fs,
                                const float* __restrict__ bias,
                                void* __restrict__ out, int nnodes) {
  int gid = blockIdx.x * blockDim.x + threadIdx.x;
  int v = gid >> 6;
  int lane = threadIdx.x & 63;
  if (v >= nnodes) return;
  int h = lane >> 3;
  int row0 = rowstart[v];
  int deg = rowstart[v + 1] - row0;
  float er_vh = er[v * NHEAD + h];
  float4 acc = make_float4(0.f, 0.f, 0.f, 0.f);
  float wsum = 0.f;
  for (int base = 0; base < deg; base += 64) {
    int mrem = deg - base;
    int mm = (mrem < 64) ? mrem : 64;
    int li = (lane < mm) ? lane : (mm - 1);
    int es = esrc[row0 + base + li];   // one coalesced load per 64 edges
    for (int j0 = 0; j0 < mm; j0 += 4) {
      int s0 = __shfl(es, j0);
      int s1 = __shfl(es, j0 + 1);
      int s2 = __shfl(es, j0 + 2);
      int s3 = __shfl(es, j0 + 3);
      float e0 = el[s0 * NHEAD + h];
      float e1 = el[s1 * NHEAD + h];
      float e2 = el[s2 * NHEAD + h];
      float e3 = el[s3 * NHEAD + h];
      ushort4 f0 = *(const ushort4*)&fs[(size_t)s0 * FDIM + lane * 4];
      ushort4 f1 = *(const ushort4*)&fs[(size_t)s1 * FDIM + lane * 4];
      ushort4 f2 = *(const ushort4*)&fs[(size_t)s2 * FDIM + lane * 4];
      ushort4 f3 = *(const ushort4*)&fs[(size_t)s3 * FDIM + lane * 4];
      #define AGG_STEP(tt, ev, fv)                                       \
      {                                                                  \
        float x = (ev) + er_vh;                                          \
        x = (x >= 0.f) ? x : SLOPE * x;                                  \
        float wgt = __expf(x);                                           \
        if (j0 + (tt) >= mm) wgt = 0.f;                                  \
        wsum += wgt;                                                     \
        acc.x = fmaf(wgt, b2f((fv).x), acc.x);                           \
        acc.y = fmaf(wgt, b2f((fv).y), acc.y);                           \
        acc.z = fmaf(wgt, b2f((fv).z), acc.z);                           \
        acc.w = fmaf(wgt, b2f((fv).w), acc.w);                           \
      }
      AGG_STEP(0, e0, f0)
      AGG_STEP(1, e1, f1)
      AGG_STEP(2, e2, f2)
      AGG_STEP(3, e3, f3)
      #undef AGG_STEP
    }
  }
  float rdenom = (deg > 0) ? (1.0f / wsum) : 0.f;
  const float4 b = *(const float4*)(bias + lane * 4);
  acc.x = fmaf(acc.x, rdenom, b.x);
  acc.y = fmaf(acc.y, rdenom, b.y);
  acc.z = fmaf(acc.z, rdenom, b.z);
  acc.w = fmaf(acc.w, rdenom, b.w);
  if (RELU) {
    acc.x = fmaxf(acc.x, 0.f); acc.y = fmaxf(acc.y, 0.f);
    acc.z = fmaxf(acc.z, 0.f); acc.w = fmaxf(acc.w, 0.f);
  }
  if (BF16OUT) {
    ushort4 o;
    o.x = f2bf(acc.x); o.y = f2bf(acc.y); o.z = f2bf(acc.z); o.w = f2bf(acc.w);
    *(ushort4*)((unsigned short*)out + (size_t)v * FDIM + lane * 4) = o;
  } else {
    *(float4*)((float*)out + (size_t)v * FDIM + lane * 4) = acc;
  }
}

// ---------------- per-graph sum pool (node-parallel, register-accumulated) ----------------
__global__ void pool_sum_kernel(const float* __restrict__ h2, const int* __restrict__ n2g,
                                float* __restrict__ hg, int nnodes) {
  int wave = (blockIdx.x * blockDim.x + threadIdx.x) >> 6;
  int lane = threadIdx.x & 63;
  int n0 = wave * 64;
  if (n0 >= nnodes) return;
  int n1 = min(n0 + 64, nnodes);
  int curg = n2g[n0];
  float4 acc = make_float4(0.f, 0.f, 0.f, 0.f);
  for (int n = n0; n < n1; ++n) {
    int g = n2g[n];
    if (g != curg) {
      float* p = &hg[(size_t)curg * FDIM + lane * 4];
      atomicAdd(p + 0, acc.x); atomicAdd(p + 1, acc.y);
      atomicAdd(p + 2, acc.z); atomicAdd(p + 3, acc.w);
      acc = make_float4(0.f, 0.f, 0.f, 0.f);
      curg = g;
    }
    float4 v = *(const float4*)&h2[(size_t)n * FDIM + lane * 4];
    acc.x += v.x; acc.y += v.y; acc.z += v.z; acc.w += v.w;
  }
  float* p = &hg[(size_t)curg * FDIM + lane * 4];
  atomicAdd(p + 0, acc.x); atomicAdd(p + 1, acc.y);
  atomicAdd(p + 2, acc.z); atomicAdd(p + 3, acc.w);
}

// ---------------- classifier (divides pooled sums by per-graph count) ----------------
__global__ void classifier_kernel(const float* __restrict__ hgsum, const int* __restrict__ gstart,
                                  const float* __restrict__ Wc, const float* __restrict__ bcv,
                                  float* __restrict__ out) {
  int tid = blockIdx.x * blockDim.x + threadIdx.x;
  if (tid >= N_GRAPHS * NC) return;
  int b = tid / NC, j = tid % NC;
  int cnt = gstart[b + 1] - gstart[b];
  float inv = (cnt > 0) ? (1.0f / (float)cnt) : 1.0f;
  float s = 0.f;
  for (int c = 0; c < FDIM; ++c) s += hgsum[b * FDIM + c] * Wc[c * NC + j];
  out[tid] = s * inv + bcv[j];
}

extern "C" void kernel_launch(void* const* d_in, const int* in_sizes, int n_in,
                              void* d_out, int out_size, void* d_ws, size_t ws_size,
                              hipStream_t stream) {
  const float* feat = (const float*)d_in[0];
  const int* src    = (const int*)d_in[1];
  const int* dst    = (const int*)d_in[2];
  const int* n2g    = (const int*)d_in[3];
  const float* W1  = (const float*)d_in[4];
  const float* al1 = (const float*)d_in[5];
  const float* ar1 = (const float*)d_in[6];
  const float* b1  = (const float*)d_in[7];
  const float* W2  = (const float*)d_in[8];
  const float* al2 = (const float*)d_in[9];
  const float* ar2 = (const float*)d_in[10];
  const float* b2  = (const float*)d_in[11];
  const float* Wc  = (const float*)d_in[12];
  const float* bc  = (const float*)d_in[13];
  float* out = (float*)d_out;

  char* wp = (char*)d_ws;
  auto carve = [&](size_t bytes) -> void* {
    void* p = (void*)wp;
    wp += (bytes + 255) & ~(size_t)255;
    return p;
  };
  unsigned short* fs = (unsigned short*)carve((size_t)MPAD * FDIM * 2);  // 25.6 MB bf16 (padded)
  // region R1 (51.2 MB): h1_bf lives first, then h2(f32) overwrites
  char* R1  = (char*)carve((size_t)MPAD * FDIM * 4);
  unsigned short* h1 = (unsigned short*)R1;       // [MPAD][256] bf16
  float* h2 = (float*)R1;                         // [N][256] f32 after h1 dead
  unsigned short* Wt1 = (unsigned short*)carve((size_t)256 * 128 * 2);
  unsigned short* Wt2 = (unsigned short*)carve((size_t)256 * 256 * 2);
  float* el      = (float*)carve((size_t)MPAD * NHEAD * 4);
  float* er      = (float*)carve((size_t)MPAD * NHEAD * 4);
  int* rowstart  = (int*)  carve((size_t)(N_NODES + 1) * 4);
  int* cursor    = (int*)  carve((size_t)N_NODES * 4);
  int* esrc      = (int*)  carve((size_t)N_EDGES * 4);
  int* gstart    = (int*)  carve((size_t)(N_GRAPHS + 1) * 4);
  float* hg      = (float*)carve((size_t)N_GRAPHS * FDIM * 4);
  (void)ws_size; (void)n_in; (void)in_sizes; (void)out_size;

  // CSR build + weight prep
  hipMemsetAsync(cursor, 0, (size_t)N_NODES * 4, stream);
  hipMemsetAsync(hg, 0, (size_t)N_GRAPHS * FDIM * 4, stream);
  hist_kernel<<<(N_EDGES + 255) / 256, 256, 0, stream>>>(dst, cursor, N_EDGES);
  scan_kernel<<<1, 1024, 0, stream>>>(cursor, rowstart, N_NODES);
  hipMemsetAsync(cursor, 0, (size_t)N_NODES * 4, stream);
  scatter_kernel<<<(N_EDGES + 255) / 256, 256, 0, stream>>>(src, dst, rowstart, cursor, esrc, N_EDGES);
  graph_bounds_kernel<<<(N_NODES + 255) / 256, 256, 0, stream>>>(n2g, gstart, N_NODES, N_GRAPHS);
  castT_kernel<128><<<(256 * 128 + 255) / 256, 256, 0, stream>>>(W1, Wt1);
  castT_kernel<256><<<(256 * 256 + 255) / 256, 256, 0, stream>>>(W2, Wt2);

  // layer 1 (gemm stages fp32 feat directly; writes fs + el + er)
  gemm_mfma<128, true><<<MPAD / 64, 256, 0, stream>>>(
      (const void*)feat, Wt1, fs, al1, ar1, el, er, N_NODES);
  edge_agg_kernel<true, true><<<(N_NODES * 64 + 255) / 256, 256, 0, stream>>>(
      rowstart, esrc, el, er, fs, b1, (void*)h1, N_NODES);

  // layer 2
  gemm_mfma<256, false><<<MPAD / 64, 256, 0, stream>>>(
      (const void*)h1, Wt2, fs, al2, ar2, el, er, N_NODES);
  edge_agg_kernel<false, false><<<(N_NODES * 64 + 255) / 256, 256, 0, stream>>>(
      rowstart, esrc, el, er, fs, b2, (void*)h2, N_NODES);

  // readout
  pool_sum_kernel<<<((N_NODES + 63) / 64 * 64 + 255) / 256, 256, 0, stream>>>(h2, n2g, hg, N_NODES);
  classifier_kernel<<<(N_GRAPHS * NC + 255) / 256, 256, 0, stream>>>(hg, gstart, Wc, bc, out);
}

// Round 9
// 339.614 us; speedup vs baseline: 2.3144x; 1.0981x over previous
//
#include <hip/hip_runtime.h>
#include <hip/hip_bf16.h>

#define N_NODES 50000
#define N_EDGES 500000
#define N_GRAPHS 64
#define FDIM 256   // H*HID
#define NHEAD 8
#define NC 10
#define SLOPE 0.2f
#define MPAD 50048  // N_NODES rounded up to 64
#define SCAN_NB ((N_NODES + 1023) / 1024)   // 49 blocks of 1024 elements

typedef __attribute__((ext_vector_type(8))) short bf16x8;
typedef __attribute__((ext_vector_type(4))) float f32x4;

__device__ __forceinline__ unsigned short f2bf(float f) {
  unsigned x = __float_as_uint(f);
  x += 0x7fff + ((x >> 16) & 1);   // RNE
  return (unsigned short)(x >> 16);
}
__device__ __forceinline__ float b2f(unsigned short u) {
  return __uint_as_float((unsigned)u << 16);
}

// ---------------- CSR build ----------------
__global__ void hist_kernel(const int* __restrict__ dst, int* __restrict__ deg, int E) {
  int e = blockIdx.x * blockDim.x + threadIdx.x;
  if (e < E) atomicAdd(&deg[dst[e]], 1);
}

// ---- 3-phase multi-block exclusive scan of deg[0..n) -> rowstart[0..n] ----
// phase 1: per-block (1024 elems, 256 thr x int4) local exclusive scan + block sum
__global__ void scan_local_kernel(const int* __restrict__ deg, int* __restrict__ rowstart,
                                  int* __restrict__ bsum, int n) {
  __shared__ int ws[4];
  int t = threadIdx.x, lane = t & 63, w = t >> 6;
  int base = blockIdx.x * 1024 + t * 4;
  int4 v = make_int4(0, 0, 0, 0);
  if (base + 3 < n) {
    v = *(const int4*)(deg + base);
  } else {
    if (base + 0 < n) v.x = deg[base + 0];
    if (base + 1 < n) v.y = deg[base + 1];
    if (base + 2 < n) v.z = deg[base + 2];
    if (base + 3 < n) v.w = deg[base + 3];
  }
  int s = v.x + v.y + v.z + v.w;
  int x = s;
  #pragma unroll
  for (int off = 1; off < 64; off <<= 1) {
    int y = __shfl_up(x, off);
    if (lane >= off) x += y;
  }
  if (lane == 63) ws[w] = x;
  __syncthreads();
  int woff = 0;
  #pragma unroll
  for (int i = 0; i < 4; ++i) woff += (i < w) ? ws[i] : 0;
  int excl = woff + x - s;   // exclusive prefix of this thread's 4 elements
  int4 o;
  o.x = excl;
  o.y = excl + v.x;
  o.z = excl + v.x + v.y;
  o.w = excl + v.x + v.y + v.z;
  if (base + 3 < n) {
    *(int4*)(rowstart + base) = o;
  } else {
    if (base + 0 < n) rowstart[base + 0] = o.x;
    if (base + 1 < n) rowstart[base + 1] = o.y;
    if (base + 2 < n) rowstart[base + 2] = o.z;
    if (base + 3 < n) rowstart[base + 3] = o.w;
  }
  if (t == 255) bsum[blockIdx.x] = woff + x;   // block total
}

// phase 2: one wave exclusive-scans the block sums (SCAN_NB <= 64)
__global__ void scan_bsum_kernel(int* __restrict__ bsum, int nb) {
  int lane = threadIdx.x & 63;
  int v = (lane < nb) ? bsum[lane] : 0;
  int x = v;
  #pragma unroll
  for (int off = 1; off < 64; off <<= 1) {
    int y = __shfl_up(x, off);
    if (lane >= off) x += y;
  }
  if (lane < nb) bsum[lane] = x - v;   // exclusive
}

// phase 3: add block offsets; rowstart[n] = E (known total)
__global__ void scan_add_kernel(int* __restrict__ rowstart, const int* __restrict__ bsum, int n) {
  int i = blockIdx.x * blockDim.x + threadIdx.x;
  if (i < n) rowstart[i] += bsum[i >> 10];
  if (i == 0) rowstart[n] = N_EDGES;
}

__global__ void scatter_kernel(const int* __restrict__ src, const int* __restrict__ dst,
                               const int* __restrict__ rowstart, int* __restrict__ cursor,
                               int* __restrict__ esrc, int E) {
  int e = blockIdx.x * blockDim.x + threadIdx.x;
  if (e >= E) return;
  int d = dst[e];
  int p = atomicAdd(&cursor[d], 1);
  esrc[rowstart[d] + p] = src[e];
}

// per-graph node ranges (node2graph is sorted)
__global__ void graph_bounds_kernel(const int* __restrict__ n2g, int* __restrict__ gstart,
                                    int n, int ngraph) {
  int i = blockIdx.x * blockDim.x + threadIdx.x;
  if (i >= n) return;
  int g1 = n2g[i];
  int g0 = (i == 0) ? -1 : n2g[i - 1];
  for (int g = g0 + 1; g <= g1; ++g) gstart[g] = i;
  if (i == n - 1) {
    for (int g = g1 + 1; g <= ngraph; ++g) gstart[g] = n;
  }
}

// W[K][256] fp32 -> Wt[256][K] bf16 (n-major, k contiguous)
template<int K>
__global__ void castT_kernel(const float* __restrict__ W, unsigned short* __restrict__ Wt) {
  int tid = blockIdx.x * blockDim.x + threadIdx.x;
  if (tid >= 256 * K) return;
  int n = tid / K, k = tid % K;
  Wt[(size_t)n * K + k] = f2bf(W[(size_t)k * 256 + n]);
}

// ---------------- LDS-staged MFMA GEMM + fused attention logits ----------------
// fs[node][256](bf16) = A[node][K] @ Wt^T ; el/er[node][8](f32) fused.
// Block 256 thr, tile 64 rows x 256 cols, BK=32. Coalesced global->reg staging
// (overlapped with compute), ds_write to single 20KB LDS buffer, ds_read_b128
// fragments. AF32: A is fp32 (feat), converted to bf16 during staging.
// Operand-swapped mfma => lane (q,m) of wave w owns node blk*64+w*16+m,
// channels nt*16+q*4+i; all 8 heads' el/er reduced wave-locally.
template<int K, bool AF32>
__global__ void gemm_mfma(const void* __restrict__ Avoid,
                          const unsigned short* __restrict__ Wt,
                          unsigned short* __restrict__ fs,
                          const float* __restrict__ al, const float* __restrict__ ar,
                          float* __restrict__ el, float* __restrict__ er, int nrows) {
  constexpr int KC = K / 32;
  __shared__ __align__(16) unsigned short Albs[64 * 32];    // [row][32k] 4 KB
  __shared__ __align__(16) unsigned short Wlds[256 * 32];   // [n][32k] 16 KB
  const float* Af = (const float*)Avoid;
  const unsigned short* Ab = (const unsigned short*)Avoid;
  int t = threadIdx.x;
  int lane = t & 63;
  int w = t >> 6;
  int row0 = blockIdx.x * 64;
  int m = lane & 15;
  int q = lane >> 4;
  // staging registers
  float4 a32[2];
  bf16x8 a16;
  bf16x8 wtr[4];
  int arow = t >> 2, apiece = t & 3;                 // bf16 A staging coords
  int agrow = min(row0 + arow, nrows - 1);
  int frow0 = t >> 3, fquad0 = t & 7;                // f32 A staging coords (j=0)
  int frow1 = (256 + t) >> 3, fquad1 = t & 7;        // j=1
  int fgrow0 = min(row0 + frow0, nrows - 1);
  int fgrow1 = min(row0 + frow1, nrows - 1);

  auto stage = [&](int kc) {
    if (AF32) {
      a32[0] = *(const float4*)(Af + (size_t)fgrow0 * K + kc * 32 + fquad0 * 4);
      a32[1] = *(const float4*)(Af + (size_t)fgrow1 * K + kc * 32 + fquad1 * 4);
    } else {
      a16 = *(const bf16x8*)(Ab + (size_t)agrow * K + kc * 32 + apiece * 8);
    }
    #pragma unroll
    for (int j = 0; j < 4; ++j) {
      int row = j * 64 + (t >> 2);
      wtr[j] = *(const bf16x8*)(Wt + (size_t)row * K + kc * 32 + (t & 3) * 8);
    }
  };
  auto commit = [&]() {
    if (AF32) {
      ushort4 o0, o1;
      o0.x = f2bf(a32[0].x); o0.y = f2bf(a32[0].y); o0.z = f2bf(a32[0].z); o0.w = f2bf(a32[0].w);
      o1.x = f2bf(a32[1].x); o1.y = f2bf(a32[1].y); o1.z = f2bf(a32[1].z); o1.w = f2bf(a32[1].w);
      *(ushort4*)(Albs + frow0 * 32 + fquad0 * 4) = o0;
      *(ushort4*)(Albs + frow1 * 32 + fquad1 * 4) = o1;
    } else {
      *(bf16x8*)(Albs + arow * 32 + apiece * 8) = a16;
    }
    #pragma unroll
    for (int j = 0; j < 4; ++j) {
      int row = j * 64 + (t >> 2);
      *(bf16x8*)(Wlds + row * 32 + (t & 3) * 8) = wtr[j];
    }
  };

  f32x4 acc[16];
  #pragma unroll
  for (int nt = 0; nt < 16; ++nt) acc[nt] = (f32x4){0.f, 0.f, 0.f, 0.f};

  stage(0);
  commit();
  for (int kc = 0; kc < KC; ++kc) {
    __syncthreads();                 // staged chunk visible
    if (kc + 1 < KC) stage(kc + 1);  // overlap next-chunk global loads with compute
    bf16x8 af = *(const bf16x8*)(Albs + (w * 16 + m) * 32 + q * 8);
    #pragma unroll
    for (int nt = 0; nt < 16; ++nt) {
      bf16x8 bfv = *(const bf16x8*)(Wlds + (nt * 16 + m) * 32 + q * 8);
      acc[nt] = __builtin_amdgcn_mfma_f32_16x16x32_bf16(bfv, af, acc[nt], 0, 0, 0);
    }
    __syncthreads();                 // all reads of chunk done
    if (kc + 1 < KC) commit();
  }

  int node = row0 + w * 16 + m;
  // fused el/er over all 8 heads
  float elh[NHEAD], erh[NHEAD];
  #pragma unroll
  for (int h = 0; h < NHEAD; ++h) { elh[h] = 0.f; erh[h] = 0.f; }
  #pragma unroll
  for (int nt = 0; nt < 16; ++nt) {
    int h = nt >> 1;
    int c0 = (nt & 1) * 16 + q * 4;
    float4 a4 = *(const float4*)(al + h * 32 + c0);
    float4 r4 = *(const float4*)(ar + h * 32 + c0);
    elh[h] += acc[nt][0] * a4.x + acc[nt][1] * a4.y + acc[nt][2] * a4.z + acc[nt][3] * a4.w;
    erh[h] += acc[nt][0] * r4.x + acc[nt][1] * r4.y + acc[nt][2] * r4.z + acc[nt][3] * r4.w;
  }
  #pragma unroll
  for (int h = 0; h < NHEAD; ++h) {
    elh[h] += __shfl_xor(elh[h], 16); elh[h] += __shfl_xor(elh[h], 32);
    erh[h] += __shfl_xor(erh[h], 16); erh[h] += __shfl_xor(erh[h], 32);
  }
  // stores (fs/el/er padded to MPAD rows; pad rows garbage, never read)
  #pragma unroll
  for (int nt = 0; nt < 16; ++nt) {
    ushort4 o;
    o.x = f2bf(acc[nt][0]); o.y = f2bf(acc[nt][1]);
    o.z = f2bf(acc[nt][2]); o.w = f2bf(acc[nt][3]);
    *(ushort4*)(fs + (size_t)node * 256 + nt * 16 + q * 4) = o;
  }
  *(float2*)(el + (size_t)node * NHEAD + 2 * q) = make_float2(elh[2 * q], elh[2 * q + 1]);
  *(float2*)(er + (size_t)node * NHEAD + 2 * q) = make_float2(erh[2 * q], erh[2 * q + 1]);
}

// ---------------- fused edge softmax + aggregation: one wave per dst node ----------------
template<bool RELU, bool BF16OUT>
__global__ void edge_agg_kernel(const int* __restrict__ rowstart, const int* __restrict__ esrc,
                                const float* __restrict__ el, const float* __restrict__ er,
                                const unsigned short* __restrict__ fs,
                                const float* __restrict__ bias,
                                void* __restrict__ out, int nnodes) {
  int gid = blockIdx.x * blockDim.x + threadIdx.x;
  int v = gid >> 6;
  int lane = threadIdx.x & 63;
  if (v >= nnodes) return;
  int h = lane >> 3;
  int row0 = rowstart[v];
  int deg = rowstart[v + 1] - row0;
  float er_vh = er[v * NHEAD + h];
  float4 acc = make_float4(0.f, 0.f, 0.f, 0.f);
  float wsum = 0.f;
  for (int base = 0; base < deg; base += 64) {
    int mrem = deg - base;
    int mm = (mrem < 64) ? mrem : 64;
    int li = (lane < mm) ? lane : (mm - 1);
    int es = esrc[row0 + base + li];   // one coalesced load per 64 edges
    for (int j0 = 0; j0 < mm; j0 += 4) {
      int s0 = __shfl(es, j0);
      int s1 = __shfl(es, j0 + 1);
      int s2 = __shfl(es, j0 + 2);
      int s3 = __shfl(es, j0 + 3);
      float e0 = el[s0 * NHEAD + h];
      float e1 = el[s1 * NHEAD + h];
      float e2 = el[s2 * NHEAD + h];
      float e3 = el[s3 * NHEAD + h];
      ushort4 f0 = *(const ushort4*)&fs[(size_t)s0 * FDIM + lane * 4];
      ushort4 f1 = *(const ushort4*)&fs[(size_t)s1 * FDIM + lane * 4];
      ushort4 f2 = *(const ushort4*)&fs[(size_t)s2 * FDIM + lane * 4];
      ushort4 f3 = *(const ushort4*)&fs[(size_t)s3 * FDIM + lane * 4];
      #define AGG_STEP(tt, ev, fv)                                       \
      {                                                                  \
        float x = (ev) + er_vh;                                          \
        x = (x >= 0.f) ? x : SLOPE * x;                                  \
        float wgt = __expf(x);                                           \
        if (j0 + (tt) >= mm) wgt = 0.f;                                  \
        wsum += wgt;                                                     \
        acc.x = fmaf(wgt, b2f((fv).x), acc.x);                           \
        acc.y = fmaf(wgt, b2f((fv).y), acc.y);                           \
        acc.z = fmaf(wgt, b2f((fv).z), acc.z);                           \
        acc.w = fmaf(wgt, b2f((fv).w), acc.w);                           \
      }
      AGG_STEP(0, e0, f0)
      AGG_STEP(1, e1, f1)
      AGG_STEP(2, e2, f2)
      AGG_STEP(3, e3, f3)
      #undef AGG_STEP
    }
  }
  float rdenom = (deg > 0) ? (1.0f / wsum) : 0.f;
  const float4 b = *(const float4*)(bias + lane * 4);
  acc.x = fmaf(acc.x, rdenom, b.x);
  acc.y = fmaf(acc.y, rdenom, b.y);
  acc.z = fmaf(acc.z, rdenom, b.z);
  acc.w = fmaf(acc.w, rdenom, b.w);
  if (RELU) {
    acc.x = fmaxf(acc.x, 0.f); acc.y = fmaxf(acc.y, 0.f);
    acc.z = fmaxf(acc.z, 0.f); acc.w = fmaxf(acc.w, 0.f);
  }
  if (BF16OUT) {
    ushort4 o;
    o.x = f2bf(acc.x); o.y = f2bf(acc.y); o.z = f2bf(acc.z); o.w = f2bf(acc.w);
    *(ushort4*)((unsigned short*)out + (size_t)v * FDIM + lane * 4) = o;
  } else {
    *(float4*)((float*)out + (size_t)v * FDIM + lane * 4) = acc;
  }
}

// ---------------- per-graph sum pool (node-parallel, register-accumulated) ----------------
__global__ void pool_sum_kernel(const float* __restrict__ h2, const int* __restrict__ n2g,
                                float* __restrict__ hg, int nnodes) {
  int wave = (blockIdx.x * blockDim.x + threadIdx.x) >> 6;
  int lane = threadIdx.x & 63;
  int n0 = wave * 64;
  if (n0 >= nnodes) return;
  int n1 = min(n0 + 64, nnodes);
  int curg = n2g[n0];
  float4 acc = make_float4(0.f, 0.f, 0.f, 0.f);
  for (int n = n0; n < n1; ++n) {
    int g = n2g[n];
    if (g != curg) {
      float* p = &hg[(size_t)curg * FDIM + lane * 4];
      atomicAdd(p + 0, acc.x); atomicAdd(p + 1, acc.y);
      atomicAdd(p + 2, acc.z); atomicAdd(p + 3, acc.w);
      acc = make_float4(0.f, 0.f, 0.f, 0.f);
      curg = g;
    }
    float4 v = *(const float4*)&h2[(size_t)n * FDIM + lane * 4];
    acc.x += v.x; acc.y += v.y; acc.z += v.z; acc.w += v.w;
  }
  float* p = &hg[(size_t)curg * FDIM + lane * 4];
  atomicAdd(p + 0, acc.x); atomicAdd(p + 1, acc.y);
  atomicAdd(p + 2, acc.z); atomicAdd(p + 3, acc.w);
}

// ---------------- classifier (divides pooled sums by per-graph count) ----------------
__global__ void classifier_kernel(const float* __restrict__ hgsum, const int* __restrict__ gstart,
                                  const float* __restrict__ Wc, const float* __restrict__ bcv,
                                  float* __restrict__ out) {
  int tid = blockIdx.x * blockDim.x + threadIdx.x;
  if (tid >= N_GRAPHS * NC) return;
  int b = tid / NC, j = tid % NC;
  int cnt = gstart[b + 1] - gstart[b];
  float inv = (cnt > 0) ? (1.0f / (float)cnt) : 1.0f;
  float s = 0.f;
  for (int c = 0; c < FDIM; ++c) s += hgsum[b * FDIM + c] * Wc[c * NC + j];
  out[tid] = s * inv + bcv[j];
}

extern "C" void kernel_launch(void* const* d_in, const int* in_sizes, int n_in,
                              void* d_out, int out_size, void* d_ws, size_t ws_size,
                              hipStream_t stream) {
  const float* feat = (const float*)d_in[0];
  const int* src    = (const int*)d_in[1];
  const int* dst    = (const int*)d_in[2];
  const int* n2g    = (const int*)d_in[3];
  const float* W1  = (const float*)d_in[4];
  const float* al1 = (const float*)d_in[5];
  const float* ar1 = (const float*)d_in[6];
  const float* b1  = (const float*)d_in[7];
  const float* W2  = (const float*)d_in[8];
  const float* al2 = (const float*)d_in[9];
  const float* ar2 = (const float*)d_in[10];
  const float* b2  = (const float*)d_in[11];
  const float* Wc  = (const float*)d_in[12];
  const float* bc  = (const float*)d_in[13];
  float* out = (float*)d_out;

  char* wp = (char*)d_ws;
  auto carve = [&](size_t bytes) -> void* {
    void* p = (void*)wp;
    wp += (bytes + 255) & ~(size_t)255;
    return p;
  };
  unsigned short* fs = (unsigned short*)carve((size_t)MPAD * FDIM * 2);  // 25.6 MB bf16 (padded)
  // region R1 (51.2 MB): h1_bf lives first, then h2(f32) overwrites
  char* R1  = (char*)carve((size_t)MPAD * FDIM * 4);
  unsigned short* h1 = (unsigned short*)R1;       // [MPAD][256] bf16
  float* h2 = (float*)R1;                         // [N][256] f32 after h1 dead
  unsigned short* Wt1 = (unsigned short*)carve((size_t)256 * 128 * 2);
  unsigned short* Wt2 = (unsigned short*)carve((size_t)256 * 256 * 2);
  float* el      = (float*)carve((size_t)MPAD * NHEAD * 4);
  float* er      = (float*)carve((size_t)MPAD * NHEAD * 4);
  int* rowstart  = (int*)  carve((size_t)(N_NODES + 1) * 4);
  int* cursor    = (int*)  carve((size_t)N_NODES * 4);
  int* esrc      = (int*)  carve((size_t)N_EDGES * 4);
  int* gstart    = (int*)  carve((size_t)(N_GRAPHS + 1) * 4);
  float* hg      = (float*)carve((size_t)N_GRAPHS * FDIM * 4);
  int* bsum      = (int*)  carve((size_t)SCAN_NB * 4);
  (void)ws_size; (void)n_in; (void)in_sizes; (void)out_size;

  // CSR build + weight prep
  hipMemsetAsync(cursor, 0, (size_t)N_NODES * 4, stream);
  hipMemsetAsync(hg, 0, (size_t)N_GRAPHS * FDIM * 4, stream);
  hist_kernel<<<(N_EDGES + 255) / 256, 256, 0, stream>>>(dst, cursor, N_EDGES);
  scan_local_kernel<<<SCAN_NB, 256, 0, stream>>>(cursor, rowstart, bsum, N_NODES);
  scan_bsum_kernel<<<1, 64, 0, stream>>>(bsum, SCAN_NB);
  scan_add_kernel<<<(N_NODES + 255) / 256, 256, 0, stream>>>(rowstart, bsum, N_NODES);
  hipMemsetAsync(cursor, 0, (size_t)N_NODES * 4, stream);
  scatter_kernel<<<(N_EDGES + 255) / 256, 256, 0, stream>>>(src, dst, rowstart, cursor, esrc, N_EDGES);
  graph_bounds_kernel<<<(N_NODES + 255) / 256, 256, 0, stream>>>(n2g, gstart, N_NODES, N_GRAPHS);
  castT_kernel<128><<<(256 * 128 + 255) / 256, 256, 0, stream>>>(W1, Wt1);
  castT_kernel<256><<<(256 * 256 + 255) / 256, 256, 0, stream>>>(W2, Wt2);

  // layer 1 (gemm stages fp32 feat directly; writes fs + el + er)
  gemm_mfma<128, true><<<MPAD / 64, 256, 0, stream>>>(
      (const void*)feat, Wt1, fs, al1, ar1, el, er, N_NODES);
  edge_agg_kernel<true, true><<<(N_NODES * 64 + 255) / 256, 256, 0, stream>>>(
      rowstart, esrc, el, er, fs, b1, (void*)h1, N_NODES);

  // layer 2
  gemm_mfma<256, false><<<MPAD / 64, 256, 0, stream>>>(
      (const void*)h1, Wt2, fs, al2, ar2, el, er, N_NODES);
  edge_agg_kernel<false, false><<<(N_NODES * 64 + 255) / 256, 256, 0, stream>>>(
      rowstart, esrc, el, er, fs, b2, (void*)h2, N_NODES);

  // readout
  pool_sum_kernel<<<((N_NODES + 63) / 64 * 64 + 255) / 256, 256, 0, stream>>>(h2, n2g, hg, N_NODES);
  classifier_kernel<<<(N_GRAPHS * NC + 255) / 256, 256, 0, stream>>>(hg, gstart, Wc, bc, out);
}

// Round 10
// 329.494 us; speedup vs baseline: 2.3854x; 1.0307x over previous
//
#include <hip/hip_runtime.h>
#include <hip/hip_bf16.h>

#define N_NODES 50000
#define N_EDGES 500000
#define N_GRAPHS 64
#define FDIM 256   // H*HID
#define NHEAD 8
#define NC 10
#define SLOPE 0.2f
#define MPAD 50048  // N_NODES rounded up to 64
#define SCAN_NB ((N_NODES + 1023) / 1024)   // 49 blocks of 1024 elements

typedef __attribute__((ext_vector_type(8))) short bf16x8;
typedef __attribute__((ext_vector_type(4))) float f32x4;

__device__ __forceinline__ unsigned short f2bf(float f) {
  unsigned x = __float_as_uint(f);
  x += 0x7fff + ((x >> 16) & 1);   // RNE
  return (unsigned short)(x >> 16);
}
__device__ __forceinline__ float b2f(unsigned short u) {
  return __uint_as_float((unsigned)u << 16);
}

// ---------------- CSR build ----------------
__global__ void hist_kernel(const int* __restrict__ dst, int* __restrict__ deg, int E) {
  int e = blockIdx.x * blockDim.x + threadIdx.x;
  if (e < E) atomicAdd(&deg[dst[e]], 1);
}

// ---- 3-phase multi-block exclusive scan of deg[0..n) -> rowstart[0..n] ----
__global__ void scan_local_kernel(const int* __restrict__ deg, int* __restrict__ rowstart,
                                  int* __restrict__ bsum, int n) {
  __shared__ int ws[4];
  int t = threadIdx.x, lane = t & 63, w = t >> 6;
  int base = blockIdx.x * 1024 + t * 4;
  int4 v = make_int4(0, 0, 0, 0);
  if (base + 3 < n) {
    v = *(const int4*)(deg + base);
  } else {
    if (base + 0 < n) v.x = deg[base + 0];
    if (base + 1 < n) v.y = deg[base + 1];
    if (base + 2 < n) v.z = deg[base + 2];
    if (base + 3 < n) v.w = deg[base + 3];
  }
  int s = v.x + v.y + v.z + v.w;
  int x = s;
  #pragma unroll
  for (int off = 1; off < 64; off <<= 1) {
    int y = __shfl_up(x, off);
    if (lane >= off) x += y;
  }
  if (lane == 63) ws[w] = x;
  __syncthreads();
  int woff = 0;
  #pragma unroll
  for (int i = 0; i < 4; ++i) woff += (i < w) ? ws[i] : 0;
  int excl = woff + x - s;
  int4 o;
  o.x = excl;
  o.y = excl + v.x;
  o.z = excl + v.x + v.y;
  o.w = excl + v.x + v.y + v.z;
  if (base + 3 < n) {
    *(int4*)(rowstart + base) = o;
  } else {
    if (base + 0 < n) rowstart[base + 0] = o.x;
    if (base + 1 < n) rowstart[base + 1] = o.y;
    if (base + 2 < n) rowstart[base + 2] = o.z;
    if (base + 3 < n) rowstart[base + 3] = o.w;
  }
  if (t == 255) bsum[blockIdx.x] = woff + x;
}

__global__ void scan_bsum_kernel(int* __restrict__ bsum, int nb) {
  int lane = threadIdx.x & 63;
  int v = (lane < nb) ? bsum[lane] : 0;
  int x = v;
  #pragma unroll
  for (int off = 1; off < 64; off <<= 1) {
    int y = __shfl_up(x, off);
    if (lane >= off) x += y;
  }
  if (lane < nb) bsum[lane] = x - v;
}

// phase 3 + graph_bounds fused (both are element-per-node passes)
__global__ void scan_add_gb_kernel(int* __restrict__ rowstart, const int* __restrict__ bsum,
                                   const int* __restrict__ n2g, int* __restrict__ gstart, int n) {
  int i = blockIdx.x * blockDim.x + threadIdx.x;
  if (i < n) {
    rowstart[i] += bsum[i >> 10];
    int g1 = n2g[i];
    int g0 = (i == 0) ? -1 : n2g[i - 1];
    for (int g = g0 + 1; g <= g1; ++g) gstart[g] = i;
    if (i == n - 1) {
      for (int g = g1 + 1; g <= N_GRAPHS; ++g) gstart[g] = n;
    }
  }
  if (i == 0) rowstart[n] = N_EDGES;
}

__global__ void scatter_kernel(const int* __restrict__ src, const int* __restrict__ dst,
                               const int* __restrict__ rowstart, int* __restrict__ cursor,
                               int* __restrict__ esrc, int E) {
  int e = blockIdx.x * blockDim.x + threadIdx.x;
  if (e >= E) return;
  int d = dst[e];
  int p = atomicAdd(&cursor[d], 1);
  esrc[rowstart[d] + p] = src[e];
}

// both weight transposes in one launch: W[K][256] f32 -> Wt[256][K] bf16
__global__ void castT_both_kernel(const float* __restrict__ W1, const float* __restrict__ W2,
                                  unsigned short* __restrict__ Wt1, unsigned short* __restrict__ Wt2) {
  int tid = blockIdx.x * blockDim.x + threadIdx.x;
  if (tid < 256 * 128) {
    int n = tid / 128, k = tid % 128;
    Wt1[(size_t)n * 128 + k] = f2bf(W1[(size_t)k * 256 + n]);
  } else if (tid < 256 * 128 + 256 * 256) {
    int t2 = tid - 256 * 128;
    int n = t2 / 256, k = t2 % 256;
    Wt2[(size_t)n * 256 + k] = f2bf(W2[(size_t)k * 256 + n]);
  }
}

// ---------------- LDS-staged MFMA GEMM + fused attention logits ----------------
template<int K, bool AF32>
__global__ void gemm_mfma(const void* __restrict__ Avoid,
                          const unsigned short* __restrict__ Wt,
                          unsigned short* __restrict__ fs,
                          const float* __restrict__ al, const float* __restrict__ ar,
                          float* __restrict__ el, float* __restrict__ er, int nrows) {
  constexpr int KC = K / 32;
  __shared__ __align__(16) unsigned short Albs[64 * 32];    // [row][32k] 4 KB
  __shared__ __align__(16) unsigned short Wlds[256 * 32];   // [n][32k] 16 KB
  const float* Af = (const float*)Avoid;
  const unsigned short* Ab = (const unsigned short*)Avoid;
  int t = threadIdx.x;
  int lane = t & 63;
  int w = t >> 6;
  int row0 = blockIdx.x * 64;
  int m = lane & 15;
  int q = lane >> 4;
  float4 a32[2];
  bf16x8 a16;
  bf16x8 wtr[4];
  int arow = t >> 2, apiece = t & 3;
  int agrow = min(row0 + arow, nrows - 1);
  int frow0 = t >> 3, fquad0 = t & 7;
  int frow1 = (256 + t) >> 3, fquad1 = t & 7;
  int fgrow0 = min(row0 + frow0, nrows - 1);
  int fgrow1 = min(row0 + frow1, nrows - 1);

  auto stage = [&](int kc) {
    if (AF32) {
      a32[0] = *(const float4*)(Af + (size_t)fgrow0 * K + kc * 32 + fquad0 * 4);
      a32[1] = *(const float4*)(Af + (size_t)fgrow1 * K + kc * 32 + fquad1 * 4);
    } else {
      a16 = *(const bf16x8*)(Ab + (size_t)agrow * K + kc * 32 + apiece * 8);
    }
    #pragma unroll
    for (int j = 0; j < 4; ++j) {
      int row = j * 64 + (t >> 2);
      wtr[j] = *(const bf16x8*)(Wt + (size_t)row * K + kc * 32 + (t & 3) * 8);
    }
  };
  auto commit = [&]() {
    if (AF32) {
      ushort4 o0, o1;
      o0.x = f2bf(a32[0].x); o0.y = f2bf(a32[0].y); o0.z = f2bf(a32[0].z); o0.w = f2bf(a32[0].w);
      o1.x = f2bf(a32[1].x); o1.y = f2bf(a32[1].y); o1.z = f2bf(a32[1].z); o1.w = f2bf(a32[1].w);
      *(ushort4*)(Albs + frow0 * 32 + fquad0 * 4) = o0;
      *(ushort4*)(Albs + frow1 * 32 + fquad1 * 4) = o1;
    } else {
      *(bf16x8*)(Albs + arow * 32 + apiece * 8) = a16;
    }
    #pragma unroll
    for (int j = 0; j < 4; ++j) {
      int row = j * 64 + (t >> 2);
      *(bf16x8*)(Wlds + row * 32 + (t & 3) * 8) = wtr[j];
    }
  };

  f32x4 acc[16];
  #pragma unroll
  for (int nt = 0; nt < 16; ++nt) acc[nt] = (f32x4){0.f, 0.f, 0.f, 0.f};

  stage(0);
  commit();
  for (int kc = 0; kc < KC; ++kc) {
    __syncthreads();
    if (kc + 1 < KC) stage(kc + 1);
    bf16x8 af = *(const bf16x8*)(Albs + (w * 16 + m) * 32 + q * 8);
    #pragma unroll
    for (int nt = 0; nt < 16; ++nt) {
      bf16x8 bfv = *(const bf16x8*)(Wlds + (nt * 16 + m) * 32 + q * 8);
      acc[nt] = __builtin_amdgcn_mfma_f32_16x16x32_bf16(bfv, af, acc[nt], 0, 0, 0);
    }
    __syncthreads();
    if (kc + 1 < KC) commit();
  }

  int node = row0 + w * 16 + m;
  float elh[NHEAD], erh[NHEAD];
  #pragma unroll
  for (int h = 0; h < NHEAD; ++h) { elh[h] = 0.f; erh[h] = 0.f; }
  #pragma unroll
  for (int nt = 0; nt < 16; ++nt) {
    int h = nt >> 1;
    int c0 = (nt & 1) * 16 + q * 4;
    float4 a4 = *(const float4*)(al + h * 32 + c0);
    float4 r4 = *(const float4*)(ar + h * 32 + c0);
    elh[h] += acc[nt][0] * a4.x + acc[nt][1] * a4.y + acc[nt][2] * a4.z + acc[nt][3] * a4.w;
    erh[h] += acc[nt][0] * r4.x + acc[nt][1] * r4.y + acc[nt][2] * r4.z + acc[nt][3] * r4.w;
  }
  #pragma unroll
  for (int h = 0; h < NHEAD; ++h) {
    elh[h] += __shfl_xor(elh[h], 16); elh[h] += __shfl_xor(elh[h], 32);
    erh[h] += __shfl_xor(erh[h], 16); erh[h] += __shfl_xor(erh[h], 32);
  }
  #pragma unroll
  for (int nt = 0; nt < 16; ++nt) {
    ushort4 o;
    o.x = f2bf(acc[nt][0]); o.y = f2bf(acc[nt][1]);
    o.z = f2bf(acc[nt][2]); o.w = f2bf(acc[nt][3]);
    *(ushort4*)(fs + (size_t)node * 256 + nt * 16 + q * 4) = o;
  }
  *(float2*)(el + (size_t)node * NHEAD + 2 * q) = make_float2(elh[2 * q], elh[2 * q + 1]);
  *(float2*)(er + (size_t)node * NHEAD + 2 * q) = make_float2(erh[2 * q], erh[2 * q + 1]);
}

// ---------------- fused edge softmax + aggregation: one wave per dst node ----------------
// 8-wide edge groups, dual accumulators (breaks fma chains), masked final group.
template<bool RELU, bool BF16OUT>
__global__ __launch_bounds__(256, 6)
void edge_agg_kernel(const int* __restrict__ rowstart, const int* __restrict__ esrc,
                     const float* __restrict__ el, const float* __restrict__ er,
                     const unsigned short* __restrict__ fs,
                     const float* __restrict__ bias,
                     void* __restrict__ out, int nnodes) {
  int gid = blockIdx.x * blockDim.x + threadIdx.x;
  int v = gid >> 6;
  int lane = threadIdx.x & 63;
  if (v >= nnodes) return;
  int h = lane >> 3;
  int row0 = rowstart[v];
  int deg = rowstart[v + 1] - row0;
  float er_vh = er[v * NHEAD + h];
  const unsigned short* fsl = fs + lane * 4;
  const float* elp = el + h;
  float4 acc0 = make_float4(0.f, 0.f, 0.f, 0.f);
  float4 acc1 = make_float4(0.f, 0.f, 0.f, 0.f);
  float ws0 = 0.f, ws1 = 0.f;
  for (int base = 0; base < deg; base += 64) {
    int mm = min(deg - base, 64);
    int li = (lane < mm) ? lane : (mm - 1);
    int es = esrc[row0 + base + li];   // one coalesced load per 64 edges
    for (int j0 = 0; j0 < mm; j0 += 8) {
      int s[8]; float e[8]; ushort4 f[8];
      if (j0 + 8 <= mm) {
        #pragma unroll
        for (int t = 0; t < 8; ++t) s[t] = __shfl(es, j0 + t);
        #pragma unroll
        for (int t = 0; t < 8; ++t) e[t] = elp[(unsigned)s[t] * 8u];
        #pragma unroll
        for (int t = 0; t < 8; ++t) f[t] = *(const ushort4*)(fsl + ((unsigned)s[t] << 8));
        #pragma unroll
        for (int t = 0; t < 8; ++t) {
          float x = e[t] + er_vh;
          x = fmaxf(x, SLOPE * x);
          float wgt = __expf(x);
          if (t & 1) {
            ws1 += wgt;
            acc1.x = fmaf(wgt, b2f(f[t].x), acc1.x);
            acc1.y = fmaf(wgt, b2f(f[t].y), acc1.y);
            acc1.z = fmaf(wgt, b2f(f[t].z), acc1.z);
            acc1.w = fmaf(wgt, b2f(f[t].w), acc1.w);
          } else {
            ws0 += wgt;
            acc0.x = fmaf(wgt, b2f(f[t].x), acc0.x);
            acc0.y = fmaf(wgt, b2f(f[t].y), acc0.y);
            acc0.z = fmaf(wgt, b2f(f[t].z), acc0.z);
            acc0.w = fmaf(wgt, b2f(f[t].w), acc0.w);
          }
        }
      } else {
        // masked final group: clamped dup loads (L1 hits), zeroed weights
        #pragma unroll
        for (int t = 0; t < 8; ++t) s[t] = __shfl(es, min(j0 + t, mm - 1));
        #pragma unroll
        for (int t = 0; t < 8; ++t) e[t] = elp[(unsigned)s[t] * 8u];
        #pragma unroll
        for (int t = 0; t < 8; ++t) f[t] = *(const ushort4*)(fsl + ((unsigned)s[t] << 8));
        #pragma unroll
        for (int t = 0; t < 8; ++t) {
          float x = e[t] + er_vh;
          x = fmaxf(x, SLOPE * x);
          float wgt = __expf(x);
          if (j0 + t >= mm) wgt = 0.f;
          if (t & 1) {
            ws1 += wgt;
            acc1.x = fmaf(wgt, b2f(f[t].x), acc1.x);
            acc1.y = fmaf(wgt, b2f(f[t].y), acc1.y);
            acc1.z = fmaf(wgt, b2f(f[t].z), acc1.z);
            acc1.w = fmaf(wgt, b2f(f[t].w), acc1.w);
          } else {
            ws0 += wgt;
            acc0.x = fmaf(wgt, b2f(f[t].x), acc0.x);
            acc0.y = fmaf(wgt, b2f(f[t].y), acc0.y);
            acc0.z = fmaf(wgt, b2f(f[t].z), acc0.z);
            acc0.w = fmaf(wgt, b2f(f[t].w), acc0.w);
          }
        }
      }
    }
  }
  float wsum = ws0 + ws1;
  float4 acc;
  acc.x = acc0.x + acc1.x; acc.y = acc0.y + acc1.y;
  acc.z = acc0.z + acc1.z; acc.w = acc0.w + acc1.w;
  float rdenom = (deg > 0) ? (1.0f / wsum) : 0.f;
  const float4 b = *(const float4*)(bias + lane * 4);
  acc.x = fmaf(acc.x, rdenom, b.x);
  acc.y = fmaf(acc.y, rdenom, b.y);
  acc.z = fmaf(acc.z, rdenom, b.z);
  acc.w = fmaf(acc.w, rdenom, b.w);
  if (RELU) {
    acc.x = fmaxf(acc.x, 0.f); acc.y = fmaxf(acc.y, 0.f);
    acc.z = fmaxf(acc.z, 0.f); acc.w = fmaxf(acc.w, 0.f);
  }
  if (BF16OUT) {
    ushort4 o;
    o.x = f2bf(acc.x); o.y = f2bf(acc.y); o.z = f2bf(acc.z); o.w = f2bf(acc.w);
    *(ushort4*)((unsigned short*)out + (size_t)v * FDIM + lane * 4) = o;
  } else {
    *(float4*)((float*)out + (size_t)v * FDIM + lane * 4) = acc;
  }
}

// ---------------- per-graph sum pool (node-parallel, register-accumulated) ----------------
__global__ void pool_sum_kernel(const float* __restrict__ h2, const int* __restrict__ n2g,
                                float* __restrict__ hg, int nnodes) {
  int wave = (blockIdx.x * blockDim.x + threadIdx.x) >> 6;
  int lane = threadIdx.x & 63;
  int n0 = wave * 64;
  if (n0 >= nnodes) return;
  int n1 = min(n0 + 64, nnodes);
  int curg = n2g[n0];
  float4 acc = make_float4(0.f, 0.f, 0.f, 0.f);
  for (int n = n0; n < n1; ++n) {
    int g = n2g[n];
    if (g != curg) {
      float* p = &hg[(size_t)curg * FDIM + lane * 4];
      atomicAdd(p + 0, acc.x); atomicAdd(p + 1, acc.y);
      atomicAdd(p + 2, acc.z); atomicAdd(p + 3, acc.w);
      acc = make_float4(0.f, 0.f, 0.f, 0.f);
      curg = g;
    }
    float4 v = *(const float4*)&h2[(size_t)n * FDIM + lane * 4];
    acc.x += v.x; acc.y += v.y; acc.z += v.z; acc.w += v.w;
  }
  float* p = &hg[(size_t)curg * FDIM + lane * 4];
  atomicAdd(p + 0, acc.x); atomicAdd(p + 1, acc.y);
  atomicAdd(p + 2, acc.z); atomicAdd(p + 3, acc.w);
}

// ---------------- classifier (divides pooled sums by per-graph count) ----------------
__global__ void classifier_kernel(const float* __restrict__ hgsum, const int* __restrict__ gstart,
                                  const float* __restrict__ Wc, const float* __restrict__ bcv,
                                  float* __restrict__ out) {
  int tid = blockIdx.x * blockDim.x + threadIdx.x;
  if (tid >= N_GRAPHS * NC) return;
  int b = tid / NC, j = tid % NC;
  int cnt = gstart[b + 1] - gstart[b];
  float inv = (cnt > 0) ? (1.0f / (float)cnt) : 1.0f;
  float s = 0.f;
  for (int c = 0; c < FDIM; ++c) s += hgsum[b * FDIM + c] * Wc[c * NC + j];
  out[tid] = s * inv + bcv[j];
}

extern "C" void kernel_launch(void* const* d_in, const int* in_sizes, int n_in,
                              void* d_out, int out_size, void* d_ws, size_t ws_size,
                              hipStream_t stream) {
  const float* feat = (const float*)d_in[0];
  const int* src    = (const int*)d_in[1];
  const int* dst    = (const int*)d_in[2];
  const int* n2g    = (const int*)d_in[3];
  const float* W1  = (const float*)d_in[4];
  const float* al1 = (const float*)d_in[5];
  const float* ar1 = (const float*)d_in[6];
  const float* b1  = (const float*)d_in[7];
  const float* W2  = (const float*)d_in[8];
  const float* al2 = (const float*)d_in[9];
  const float* ar2 = (const float*)d_in[10];
  const float* b2  = (const float*)d_in[11];
  const float* Wc  = (const float*)d_in[12];
  const float* bc  = (const float*)d_in[13];
  float* out = (float*)d_out;

  char* wp = (char*)d_ws;
  auto carve = [&](size_t bytes) -> void* {
    void* p = (void*)wp;
    wp += (bytes + 255) & ~(size_t)255;
    return p;
  };
  unsigned short* fs = (unsigned short*)carve((size_t)MPAD * FDIM * 2);  // 25.6 MB bf16 (padded)
  // region R1 (51.2 MB): h1_bf lives first, then h2(f32) overwrites
  char* R1  = (char*)carve((size_t)MPAD * FDIM * 4);
  unsigned short* h1 = (unsigned short*)R1;       // [MPAD][256] bf16
  float* h2 = (float*)R1;                         // [N][256] f32 after h1 dead
  unsigned short* Wt1 = (unsigned short*)carve((size_t)256 * 128 * 2);
  unsigned short* Wt2 = (unsigned short*)carve((size_t)256 * 256 * 2);
  float* el      = (float*)carve((size_t)MPAD * NHEAD * 4);
  float* er      = (float*)carve((size_t)MPAD * NHEAD * 4);
  int* rowstart  = (int*)  carve((size_t)(N_NODES + 1) * 4);
  int* esrc      = (int*)  carve((size_t)N_EDGES * 4);
  int* gstart    = (int*)  carve((size_t)(N_GRAPHS + 1) * 4);
  int* bsum      = (int*)  carve((size_t)SCAN_NB * 4);
  // zero-init region: cursor + cursor2 + hg carved contiguously, single memset
  int* cursor    = (int*)  carve((size_t)N_NODES * 4);
  int* cursor2   = (int*)  carve((size_t)N_NODES * 4);
  float* hg      = (float*)carve((size_t)N_GRAPHS * FDIM * 4);
  size_t zlen = (size_t)((char*)(hg + N_GRAPHS * FDIM) - (char*)cursor);
  (void)ws_size; (void)n_in; (void)in_sizes; (void)out_size;

  // CSR build + weight prep
  hipMemsetAsync(cursor, 0, zlen, stream);   // cursor, cursor2, hg
  hist_kernel<<<(N_EDGES + 255) / 256, 256, 0, stream>>>(dst, cursor, N_EDGES);
  scan_local_kernel<<<SCAN_NB, 256, 0, stream>>>(cursor, rowstart, bsum, N_NODES);
  scan_bsum_kernel<<<1, 64, 0, stream>>>(bsum, SCAN_NB);
  scan_add_gb_kernel<<<(N_NODES + 255) / 256, 256, 0, stream>>>(rowstart, bsum, n2g, gstart, N_NODES);
  scatter_kernel<<<(N_EDGES + 255) / 256, 256, 0, stream>>>(src, dst, rowstart, cursor2, esrc, N_EDGES);
  castT_both_kernel<<<(256 * 128 + 256 * 256 + 255) / 256, 256, 0, stream>>>(W1, W2, Wt1, Wt2);

  // layer 1 (gemm stages fp32 feat directly; writes fs + el + er)
  gemm_mfma<128, true><<<MPAD / 64, 256, 0, stream>>>(
      (const void*)feat, Wt1, fs, al1, ar1, el, er, N_NODES);
  edge_agg_kernel<true, true><<<(N_NODES * 64 + 255) / 256, 256, 0, stream>>>(
      rowstart, esrc, el, er, fs, b1, (void*)h1, N_NODES);

  // layer 2
  gemm_mfma<256, false><<<MPAD / 64, 256, 0, stream>>>(
      (const void*)h1, Wt2, fs, al2, ar2, el, er, N_NODES);
  edge_agg_kernel<false, false><<<(N_NODES * 64 + 255) / 256, 256, 0, stream>>>(
      rowstart, esrc, el, er, fs, b2, (void*)h2, N_NODES);

  // readout
  pool_sum_kernel<<<((N_NODES + 63) / 64 * 64 + 255) / 256, 256, 0, stream>>>(h2, n2g, hg, N_NODES);
  classifier_kernel<<<(N_GRAPHS * NC + 255) / 256, 256, 0, stream>>>(hg, gstart, Wc, bc, out);
}